// Round 5
// baseline (392.704 us; speedup 1.0000x reference)
//
#include <hip/hip_runtime.h>
#include <math.h>

#define NN 100000
#define NE 1600000
#define SCAN_CH 1024
#define SCAN_NBLK ((NN + SCAN_CH - 1) / SCAN_CH)   // 98
#define EPT 8                                       // edges per thread in CSR build
#define NT ((NE + EPT - 1) / EPT)                   // 200000 threads

typedef __attribute__((ext_vector_type(8))) short bf16x8;   // 8 bf16 = 4 VGPR (MFMA A/B frag)
typedef __attribute__((ext_vector_type(8))) unsigned short ush8;
typedef __attribute__((ext_vector_type(4))) float f32x4;    // MFMA C/D frag

static __device__ __forceinline__ float b2f(unsigned short u) {
    return __uint_as_float(((unsigned int)u) << 16);
}
static __device__ __forceinline__ unsigned short f2bf(float f) {
    unsigned int u = __float_as_uint(f);
    u += 0x7fffu + ((u >> 16) & 1u);   // RNE
    return (unsigned short)(u >> 16);
}

// ---------------- conversions ----------------
__global__ __launch_bounds__(256)
void k_cvt_x(const float* __restrict__ in, unsigned short* __restrict__ outb, long total8) {
    long i = (long)blockIdx.x * 256 + threadIdx.x;
    long stride = (long)gridDim.x * 256;
    for (; i < total8; i += stride) {
        const float4* p = (const float4*)(in + i * 8);
        float4 a = p[0], b = p[1];
        ush8 r;
        r[0] = f2bf(a.x); r[1] = f2bf(a.y); r[2] = f2bf(a.z); r[3] = f2bf(a.w);
        r[4] = f2bf(b.x); r[5] = f2bf(b.y); r[6] = f2bf(b.z); r[7] = f2bf(b.w);
        *(ush8*)(outb + i * 8) = r;
    }
}

// W [128, N] f32 -> Wt [N, 128] bf16 (row-major over n)
__global__ __launch_bounds__(256)
void k_cvt_w(const float* __restrict__ W, unsigned short* __restrict__ Wt, int N) {
    int id = blockIdx.x * 256 + threadIdx.x;
    if (id < N * 128) {
        int n = id >> 7, k = id & 127;
        Wt[id] = f2bf(W[k * N + n]);
    }
}

// ---------------- CSR build (8 edges/thread for MLP) ----------------
__global__ __launch_bounds__(256)
void k_count_deg(const int* __restrict__ dst, int* __restrict__ deg) {
    int t = blockIdx.x * 256 + threadIdx.x;
    if (t >= NT) return;
    int d[EPT];
    #pragma unroll
    for (int k = 0; k < EPT; ++k) d[k] = dst[t + k * NT];
    #pragma unroll
    for (int k = 0; k < EPT; ++k) atomicAdd(&deg[d[k]], 1);
}

__global__ __launch_bounds__(256)
void k_block_scan(const int* __restrict__ deg, int* __restrict__ offs, int* __restrict__ bsum) {
    __shared__ int tsum[256];
    const int b = blockIdx.x, t = threadIdx.x;
    const int base = b * SCAN_CH + t * 4;
    int v[4]; int s = 0;
    #pragma unroll
    for (int i = 0; i < 4; ++i) { int idx = base + i; v[i] = (idx < NN) ? deg[idx] : 0; s += v[i]; }
    tsum[t] = s;
    __syncthreads();
    for (int d = 1; d < 256; d <<= 1) {
        int u = (t >= d) ? tsum[t - d] : 0;
        __syncthreads();
        tsum[t] += u;
        __syncthreads();
    }
    int excl = tsum[t] - s;
    #pragma unroll
    for (int i = 0; i < 4; ++i) { int idx = base + i; if (idx < NN) { offs[idx] = excl; excl += v[i]; } }
    if (t == 255) bsum[b] = tsum[t];
}

__global__ void k_scan_sums(int* __restrict__ bsum) {
    __shared__ int s[128];
    int t = threadIdx.x;
    int v = (t < SCAN_NBLK) ? bsum[t] : 0;
    s[t] = v;
    __syncthreads();
    for (int d = 1; d < 128; d <<= 1) {
        int u = (t >= d) ? s[t - d] : 0;
        __syncthreads();
        s[t] += u;
        __syncthreads();
    }
    if (t < SCAN_NBLK) bsum[t] = s[t] - v;
}

__global__ __launch_bounds__(256)
void k_add_base(int* __restrict__ offs, const int* __restrict__ bsum) {
    int i = blockIdx.x * 256 + threadIdx.x;
    if (i < NN) offs[i] += bsum[i >> 10];
}

__global__ __launch_bounds__(256)
void k_fill(const int* __restrict__ src, const int* __restrict__ dst,
            const int* __restrict__ offs, int* __restrict__ cur,
            int* __restrict__ csr) {
    int t = blockIdx.x * 256 + threadIdx.x;
    if (t >= NT) return;
    int d[EPT], s[EPT], of[EPT], p[EPT];
    #pragma unroll
    for (int k = 0; k < EPT; ++k) {
        int e = t + k * NT;
        d[k] = dst[e]; s[k] = src[e];
    }
    #pragma unroll
    for (int k = 0; k < EPT; ++k) of[k] = offs[d[k]];
    #pragma unroll
    for (int k = 0; k < EPT; ++k) p[k] = atomicAdd(&cur[d[k]], 1);
    #pragma unroll
    for (int k = 0; k < EPT; ++k) csr[of[k] + p[k]] = s[k];
}

// ---------------- bf16 mean aggregation: one wave per node, 4 edges/group-iter ----------------
__global__ __launch_bounds__(256)
void k_aggregate_bf(const unsigned short* __restrict__ feat, const int* __restrict__ csr,
                    const int* __restrict__ offs, const int* __restrict__ deg,
                    unsigned short* __restrict__ outmean) {
    const int wid = threadIdx.x >> 6, lane = threadIdx.x & 63;
    const int q = lane >> 4, l4 = lane & 15;
    const int node = blockIdx.x * 4 + wid;
    if (node >= NN) return;
    int off = __builtin_amdgcn_readfirstlane(offs[node]);
    int dg  = __builtin_amdgcn_readfirstlane(deg[node]);
    const ush8* __restrict__ f8 = (const ush8*)feat;
    float acc[8];
    #pragma unroll
    for (int i = 0; i < 8; ++i) acc[i] = 0.f;
    int j = 0;
    for (; j + 8 <= dg; j += 8) {
        int e0 = csr[off + j + q];
        int e1 = csr[off + j + 4 + q];
        ush8 v0 = f8[(size_t)e0 * 16 + l4];
        ush8 v1 = f8[(size_t)e1 * 16 + l4];
        #pragma unroll
        for (int i = 0; i < 8; ++i) acc[i] += b2f(v0[i]) + b2f(v1[i]);
    }
    for (; j + 4 <= dg; j += 4) {
        int e0 = csr[off + j + q];
        ush8 v0 = f8[(size_t)e0 * 16 + l4];
        #pragma unroll
        for (int i = 0; i < 8; ++i) acc[i] += b2f(v0[i]);
    }
    int rem = dg - j;
    if (q < rem) {
        int e0 = csr[off + j + q];
        ush8 v0 = f8[(size_t)e0 * 16 + l4];
        #pragma unroll
        for (int i = 0; i < 8; ++i) acc[i] += b2f(v0[i]);
    }
    #pragma unroll
    for (int i = 0; i < 8; ++i) {
        acc[i] += __shfl_xor(acc[i], 16);
        acc[i] += __shfl_xor(acc[i], 32);
    }
    if (q == 0) {
        float inv = 1.0f / (float)(dg > 0 ? dg : 1);
        ush8 r;
        #pragma unroll
        for (int i = 0; i < 8; ++i) r[i] = f2bf(acc[i] * inv);
        ((ush8*)outmean)[(size_t)node * 16 + l4] = r;
    }
}

// ---------------- MFMA dual GEMM: out = Am@Wl + Ax@Wr + bias (+relu / +log_softmax) ----------------
// A: [NN,128] bf16. Wt: [BN,128] bf16 (pre-transposed). Block: 128 rows x BN cols, 4 waves.
template <int BN, bool RELU, bool OUTBF, bool LSM>
__global__ __launch_bounds__(256)
void k_gemm_mfma(const unsigned short* __restrict__ Am, const unsigned short* __restrict__ Ax,
                 const unsigned short* __restrict__ Wtl, const unsigned short* __restrict__ Wtr,
                 const float* __restrict__ bias, void* __restrict__ outp) {
    constexpr int BM = 128;
    constexpr int WAVES_N = BN / 64;          // 2 (BN=128) or 1 (BN=64)
    constexpr int WAVES_M = 4 / WAVES_N;      // 2 or 4
    constexpr int MR = BM / (WAVES_M * 16);   // 4 or 2
    constexpr int NR = 4;                     // 64 cols per wave
    __shared__ __align__(16) short As[BM * 40];   // 80B row stride -> uniform banks
    __shared__ __align__(16) short Ws[BN * 40];

    const int tid = threadIdx.x;
    const int wave = tid >> 6, lane = tid & 63;
    const int l15 = lane & 15, kg = lane >> 4;
    const int wc = wave % WAVES_N, wr = wave / WAVES_N;
    const int rowbase = wr * MR * 16;
    const int colbase = wc * 64;
    const int row0 = blockIdx.x * BM;

    f32x4 acc[MR][NR];
    #pragma unroll
    for (int mr = 0; mr < MR; ++mr)
        #pragma unroll
        for (int nr = 0; nr < NR; ++nr) acc[mr][nr] = (f32x4){0.f, 0.f, 0.f, 0.f};

    for (int s = 0; s < 2; ++s) {
        const unsigned short* __restrict__ A  = s ? Ax : Am;
        const unsigned short* __restrict__ Wt = s ? Wtr : Wtl;
        for (int kc = 0; kc < 128; kc += 32) {
            __syncthreads();
            #pragma unroll
            for (int i = 0; i < (BM * 4) / 256; ++i) {
                int c = tid + 256 * i; int r = c >> 2, g = c & 3;
                ush8 v = {0, 0, 0, 0, 0, 0, 0, 0};
                int grow = row0 + r;
                if (grow < NN) v = *(const ush8*)&A[(size_t)grow * 128 + kc + g * 8];
                *(ush8*)&As[r * 40 + g * 8] = v;
            }
            #pragma unroll
            for (int i = 0; i < (BN * 4) / 256; ++i) {
                int c = tid + 256 * i; int n = c >> 2, g = c & 3;
                *(ush8*)&Ws[n * 40 + g * 8] = *(const ush8*)&Wt[n * 128 + kc + g * 8];
            }
            __syncthreads();
            bf16x8 af[MR], bfr[NR];
            #pragma unroll
            for (int mr = 0; mr < MR; ++mr)
                af[mr] = *(const bf16x8*)&As[(rowbase + mr * 16 + l15) * 40 + kg * 8];
            #pragma unroll
            for (int nr = 0; nr < NR; ++nr)
                bfr[nr] = *(const bf16x8*)&Ws[(colbase + nr * 16 + l15) * 40 + kg * 8];
            #pragma unroll
            for (int mr = 0; mr < MR; ++mr)
                #pragma unroll
                for (int nr = 0; nr < NR; ++nr)
                    acc[mr][nr] = __builtin_amdgcn_mfma_f32_16x16x32_bf16(
                        af[mr], bfr[nr], acc[mr][nr], 0, 0, 0);
        }
    }
    // epilogue
    const int r4 = kg * 4;
    if (LSM) {
        // BN==64: each 16-lane group (fixed kg) holds one full 64-col row per (mr,j):
        // cols nr*16+l15. Reduce max/sum across nr (regs) then l15 (shfl_xor 1/2/4/8).
        #pragma unroll
        for (int mr = 0; mr < MR; ++mr) {
            #pragma unroll
            for (int j = 0; j < 4; ++j) {
                int row = row0 + rowbase + mr * 16 + r4 + j;
                float v[NR];
                float m = -1e30f;
                #pragma unroll
                for (int nr = 0; nr < NR; ++nr) {
                    v[nr] = acc[mr][nr][j] + bias[nr * 16 + l15];
                    m = fmaxf(m, v[nr]);
                }
                #pragma unroll
                for (int d = 8; d >= 1; d >>= 1) m = fmaxf(m, __shfl_xor(m, d));
                float ssum = 0.f;
                #pragma unroll
                for (int nr = 0; nr < NR; ++nr) ssum += __expf(v[nr] - m);
                #pragma unroll
                for (int d = 8; d >= 1; d >>= 1) ssum += __shfl_xor(ssum, d);
                float lse = m + logf(ssum);
                if (row < NN) {
                    #pragma unroll
                    for (int nr = 0; nr < NR; ++nr)
                        ((float*)outp)[(size_t)row * 64 + nr * 16 + l15] = v[nr] - lse;
                }
            }
        }
    } else {
        #pragma unroll
        for (int mr = 0; mr < MR; ++mr) {
            #pragma unroll
            for (int nr = 0; nr < NR; ++nr) {
                int col = colbase + nr * 16 + l15;
                float bv = bias[col];
                #pragma unroll
                for (int j = 0; j < 4; ++j) {
                    int row = row0 + rowbase + mr * 16 + r4 + j;
                    if (row < NN) {
                        float v = acc[mr][nr][j] + bv;
                        if (RELU) v = fmaxf(v, 0.f);
                        if (OUTBF) ((unsigned short*)outp)[(size_t)row * BN + col] = f2bf(v);
                        else       ((float*)outp)[(size_t)row * BN + col] = v;
                    }
                }
            }
        }
    }
}

// ---------------- launch ----------------
extern "C" void kernel_launch(void* const* d_in, const int* in_sizes, int n_in,
                              void* d_out, int out_size, void* d_ws, size_t ws_size,
                              hipStream_t stream) {
    const float* x   = (const float*)d_in[0];
    const int* edges = (const int*)d_in[1];
    const float* W1l = (const float*)d_in[2];
    const float* b1  = (const float*)d_in[3];
    const float* W1r = (const float*)d_in[4];
    const float* W2l = (const float*)d_in[5];
    const float* b2  = (const float*)d_in[6];
    const float* W2r = (const float*)d_in[7];
    float* out = (float*)d_out;

    const int* src = edges;            // edge_index[0]
    const int* dst = edges + NE;       // edge_index[1]

    char* ws = (char*)d_ws;
    size_t o = 0;
    auto alloc = [&](size_t bytes) -> void* {
        void* p = ws + o;
        o = (o + bytes + 255) & ~(size_t)255;
        return p;
    };
    int* deg  = (int*)alloc((size_t)NN * 4);
    int* offs = (int*)alloc((size_t)NN * 4);
    int* cur  = (int*)alloc((size_t)NN * 4);
    int* bsum = (int*)alloc((size_t)SCAN_NBLK * 4);
    int* csr  = (int*)alloc((size_t)NE * 4);
    unsigned short* xb    = (unsigned short*)alloc((size_t)NN * 128 * 2);
    unsigned short* meanb = (unsigned short*)alloc((size_t)NN * 128 * 2);
    unsigned short* hb    = (unsigned short*)alloc((size_t)NN * 128 * 2);
    unsigned short* Wt1l  = (unsigned short*)alloc(128 * 128 * 2);
    unsigned short* Wt1r  = (unsigned short*)alloc(128 * 128 * 2);
    unsigned short* Wt2l  = (unsigned short*)alloc(64 * 128 * 2);
    unsigned short* Wt2r  = (unsigned short*)alloc(64 * 128 * 2);

    hipMemsetAsync(deg, 0, (size_t)NN * 4, stream);
    hipMemsetAsync(cur, 0, (size_t)NN * 4, stream);

    // conversions
    k_cvt_x<<<2048, 256, 0, stream>>>(x, xb, (long)NN * 128 / 8);
    k_cvt_w<<<(128 * 128 + 255) / 256, 256, 0, stream>>>(W1l, Wt1l, 128);
    k_cvt_w<<<(128 * 128 + 255) / 256, 256, 0, stream>>>(W1r, Wt1r, 128);
    k_cvt_w<<<(64 * 128 + 255) / 256, 256, 0, stream>>>(W2l, Wt2l, 64);
    k_cvt_w<<<(64 * 128 + 255) / 256, 256, 0, stream>>>(W2r, Wt2r, 64);

    // CSR build
    k_count_deg<<<(NT + 255) / 256, 256, 0, stream>>>(dst, deg);
    k_block_scan<<<SCAN_NBLK, 256, 0, stream>>>(deg, offs, bsum);
    k_scan_sums<<<1, 128, 0, stream>>>(bsum);
    k_add_base<<<(NN + 255) / 256, 256, 0, stream>>>(offs, bsum);
    k_fill<<<(NT + 255) / 256, 256, 0, stream>>>(src, dst, offs, cur, csr);

    const int GEMM_GRID = (NN + 127) / 128;   // 782
    // layer 1
    k_aggregate_bf<<<NN / 4, 256, 0, stream>>>(xb, csr, offs, deg, meanb);
    k_gemm_mfma<128, true, true, false><<<GEMM_GRID, 256, 0, stream>>>(meanb, xb, Wt1l, Wt1r, b1, hb);
    // layer 2 (log_softmax fused into GEMM epilogue)
    k_aggregate_bf<<<NN / 4, 256, 0, stream>>>(hb, csr, offs, deg, meanb);
    k_gemm_mfma<64, false, false, true><<<GEMM_GRID, 256, 0, stream>>>(meanb, hb, Wt2l, Wt2r, b2, out);
}

// Round 6
// 311.560 us; speedup vs baseline: 1.2604x; 1.2604x over previous
//
#include <hip/hip_runtime.h>
#include <math.h>

#define NN 100000
#define NE 1600000
#define SCAN_CH 1024
#define SCAN_NBLK ((NN + SCAN_CH - 1) / SCAN_CH)   // 98

typedef __attribute__((ext_vector_type(8))) short bf16x8;   // 8 bf16 = 4 VGPR (MFMA A/B frag)
typedef __attribute__((ext_vector_type(8))) unsigned short ush8;
typedef __attribute__((ext_vector_type(4))) float f32x4;    // MFMA C/D frag

static __device__ __forceinline__ float b2f(unsigned short u) {
    return __uint_as_float(((unsigned int)u) << 16);
}
static __device__ __forceinline__ unsigned short f2bf(float f) {
    unsigned int u = __float_as_uint(f);
    u += 0x7fffu + ((u >> 16) & 1u);   // RNE
    return (unsigned short)(u >> 16);
}

// ---------------- conversions ----------------
__global__ __launch_bounds__(256)
void k_cvt_x(const float* __restrict__ in, unsigned short* __restrict__ outb, long total8) {
    long i = (long)blockIdx.x * 256 + threadIdx.x;
    long stride = (long)gridDim.x * 256;
    for (; i < total8; i += stride) {
        const float4* p = (const float4*)(in + i * 8);
        float4 a = p[0], b = p[1];
        ush8 r;
        r[0] = f2bf(a.x); r[1] = f2bf(a.y); r[2] = f2bf(a.z); r[3] = f2bf(a.w);
        r[4] = f2bf(b.x); r[5] = f2bf(b.y); r[6] = f2bf(b.z); r[7] = f2bf(b.w);
        *(ush8*)(outb + i * 8) = r;
    }
}

// W [128, N] f32 -> Wt [N, 128] bf16 (row-major over n)
__global__ __launch_bounds__(256)
void k_cvt_w(const float* __restrict__ W, unsigned short* __restrict__ Wt, int N) {
    int id = blockIdx.x * 256 + threadIdx.x;
    if (id < N * 128) {
        int n = id >> 7, k = id & 127;
        Wt[id] = f2bf(W[k * N + n]);
    }
}

// ---------------- CSR build: rank-then-place (single atomic pass) ----------------
__global__ __launch_bounds__(256)
void k_rank(const int* __restrict__ dst, int* __restrict__ deg, int* __restrict__ rank) {
    int e = blockIdx.x * 256 + threadIdx.x;
    if (e < NE) {
        int d = dst[e];
        rank[e] = atomicAdd(&deg[d], 1);
    }
}

__global__ __launch_bounds__(256)
void k_block_scan(const int* __restrict__ deg, int* __restrict__ offs, int* __restrict__ bsum) {
    __shared__ int tsum[256];
    const int b = blockIdx.x, t = threadIdx.x;
    const int base = b * SCAN_CH + t * 4;
    int v[4]; int s = 0;
    #pragma unroll
    for (int i = 0; i < 4; ++i) { int idx = base + i; v[i] = (idx < NN) ? deg[idx] : 0; s += v[i]; }
    tsum[t] = s;
    __syncthreads();
    for (int d = 1; d < 256; d <<= 1) {
        int u = (t >= d) ? tsum[t - d] : 0;
        __syncthreads();
        tsum[t] += u;
        __syncthreads();
    }
    int excl = tsum[t] - s;
    #pragma unroll
    for (int i = 0; i < 4; ++i) { int idx = base + i; if (idx < NN) { offs[idx] = excl; excl += v[i]; } }
    if (t == 255) bsum[b] = tsum[t];
}

__global__ void k_scan_sums(int* __restrict__ bsum) {
    __shared__ int s[128];
    int t = threadIdx.x;
    int v = (t < SCAN_NBLK) ? bsum[t] : 0;
    s[t] = v;
    __syncthreads();
    for (int d = 1; d < 128; d <<= 1) {
        int u = (t >= d) ? s[t - d] : 0;
        __syncthreads();
        s[t] += u;
        __syncthreads();
    }
    if (t < SCAN_NBLK) bsum[t] = s[t] - v;
}

__global__ __launch_bounds__(256)
void k_add_base(int* __restrict__ offs, const int* __restrict__ bsum) {
    int i = blockIdx.x * 256 + threadIdx.x;
    if (i < NN) offs[i] += bsum[i >> 10];
}

// atomic-free scatter: csr[offs[d] + rank] = src
__global__ __launch_bounds__(256)
void k_place(const int* __restrict__ src, const int* __restrict__ dst,
             const int* __restrict__ offs, const int* __restrict__ rank,
             int* __restrict__ csr) {
    int e = blockIdx.x * 256 + threadIdx.x;
    if (e < NE) {
        int d = dst[e];
        int r = rank[e];
        int s = src[e];
        __builtin_nontemporal_store(s, &csr[offs[d] + r]);
    }
}

// ---------------- bf16 mean aggregation: one wave per node, 4 edges/group-iter ----------------
__global__ __launch_bounds__(256)
void k_aggregate_bf(const unsigned short* __restrict__ feat, const int* __restrict__ csr,
                    const int* __restrict__ offs, const int* __restrict__ deg,
                    unsigned short* __restrict__ outmean) {
    const int wid = threadIdx.x >> 6, lane = threadIdx.x & 63;
    const int q = lane >> 4, l4 = lane & 15;
    const int node = blockIdx.x * 4 + wid;
    if (node >= NN) return;
    int off = __builtin_amdgcn_readfirstlane(offs[node]);
    int dg  = __builtin_amdgcn_readfirstlane(deg[node]);
    const ush8* __restrict__ f8 = (const ush8*)feat;
    float acc[8];
    #pragma unroll
    for (int i = 0; i < 8; ++i) acc[i] = 0.f;
    int j = 0;
    for (; j + 8 <= dg; j += 8) {
        int e0 = csr[off + j + q];
        int e1 = csr[off + j + 4 + q];
        ush8 v0 = f8[(size_t)e0 * 16 + l4];
        ush8 v1 = f8[(size_t)e1 * 16 + l4];
        #pragma unroll
        for (int i = 0; i < 8; ++i) acc[i] += b2f(v0[i]) + b2f(v1[i]);
    }
    for (; j + 4 <= dg; j += 4) {
        int e0 = csr[off + j + q];
        ush8 v0 = f8[(size_t)e0 * 16 + l4];
        #pragma unroll
        for (int i = 0; i < 8; ++i) acc[i] += b2f(v0[i]);
    }
    int rem = dg - j;
    if (q < rem) {
        int e0 = csr[off + j + q];
        ush8 v0 = f8[(size_t)e0 * 16 + l4];
        #pragma unroll
        for (int i = 0; i < 8; ++i) acc[i] += b2f(v0[i]);
    }
    #pragma unroll
    for (int i = 0; i < 8; ++i) {
        acc[i] += __shfl_xor(acc[i], 16);
        acc[i] += __shfl_xor(acc[i], 32);
    }
    if (q == 0) {
        float inv = 1.0f / (float)(dg > 0 ? dg : 1);
        ush8 r;
        #pragma unroll
        for (int i = 0; i < 8; ++i) r[i] = f2bf(acc[i] * inv);
        ((ush8*)outmean)[(size_t)node * 16 + l4] = r;
    }
}

// ---------------- MFMA dual GEMM: out = Am@Wl + Ax@Wr + bias (+relu / +log_softmax) ----------------
// A: [NN,128] bf16. Wt: [BN,128] bf16 (pre-transposed). Block: 128 rows x BN cols, 4 waves.
template <int BN, bool RELU, bool OUTBF, bool LSM>
__global__ __launch_bounds__(256)
void k_gemm_mfma(const unsigned short* __restrict__ Am, const unsigned short* __restrict__ Ax,
                 const unsigned short* __restrict__ Wtl, const unsigned short* __restrict__ Wtr,
                 const float* __restrict__ bias, void* __restrict__ outp) {
    constexpr int BM = 128;
    constexpr int WAVES_N = BN / 64;          // 2 (BN=128) or 1 (BN=64)
    constexpr int WAVES_M = 4 / WAVES_N;      // 2 or 4
    constexpr int MR = BM / (WAVES_M * 16);   // 4 or 2
    constexpr int NR = 4;                     // 64 cols per wave
    __shared__ __align__(16) short As[BM * 40];   // 80B row stride -> uniform banks
    __shared__ __align__(16) short Ws[BN * 40];

    const int tid = threadIdx.x;
    const int wave = tid >> 6, lane = tid & 63;
    const int l15 = lane & 15, kg = lane >> 4;
    const int wc = wave % WAVES_N, wr = wave / WAVES_N;
    const int rowbase = wr * MR * 16;
    const int colbase = wc * 64;
    const int row0 = blockIdx.x * BM;

    f32x4 acc[MR][NR];
    #pragma unroll
    for (int mr = 0; mr < MR; ++mr)
        #pragma unroll
        for (int nr = 0; nr < NR; ++nr) acc[mr][nr] = (f32x4){0.f, 0.f, 0.f, 0.f};

    for (int s = 0; s < 2; ++s) {
        const unsigned short* __restrict__ A  = s ? Ax : Am;
        const unsigned short* __restrict__ Wt = s ? Wtr : Wtl;
        for (int kc = 0; kc < 128; kc += 32) {
            __syncthreads();
            #pragma unroll
            for (int i = 0; i < (BM * 4) / 256; ++i) {
                int c = tid + 256 * i; int r = c >> 2, g = c & 3;
                ush8 v = {0, 0, 0, 0, 0, 0, 0, 0};
                int grow = row0 + r;
                if (grow < NN) v = *(const ush8*)&A[(size_t)grow * 128 + kc + g * 8];
                *(ush8*)&As[r * 40 + g * 8] = v;
            }
            #pragma unroll
            for (int i = 0; i < (BN * 4) / 256; ++i) {
                int c = tid + 256 * i; int n = c >> 2, g = c & 3;
                *(ush8*)&Ws[n * 40 + g * 8] = *(const ush8*)&Wt[n * 128 + kc + g * 8];
            }
            __syncthreads();
            bf16x8 af[MR], bfr[NR];
            #pragma unroll
            for (int mr = 0; mr < MR; ++mr)
                af[mr] = *(const bf16x8*)&As[(rowbase + mr * 16 + l15) * 40 + kg * 8];
            #pragma unroll
            for (int nr = 0; nr < NR; ++nr)
                bfr[nr] = *(const bf16x8*)&Ws[(colbase + nr * 16 + l15) * 40 + kg * 8];
            #pragma unroll
            for (int mr = 0; mr < MR; ++mr)
                #pragma unroll
                for (int nr = 0; nr < NR; ++nr)
                    acc[mr][nr] = __builtin_amdgcn_mfma_f32_16x16x32_bf16(
                        af[mr], bfr[nr], acc[mr][nr], 0, 0, 0);
        }
    }
    // epilogue
    const int r4 = kg * 4;
    if (LSM) {
        // BN==64: each 16-lane group (fixed kg) holds one full 64-col row per (mr,j):
        // cols nr*16+l15. Reduce max/sum across nr (regs) then l15 (shfl_xor 1/2/4/8).
        #pragma unroll
        for (int mr = 0; mr < MR; ++mr) {
            #pragma unroll
            for (int j = 0; j < 4; ++j) {
                int row = row0 + rowbase + mr * 16 + r4 + j;
                float v[NR];
                float m = -1e30f;
                #pragma unroll
                for (int nr = 0; nr < NR; ++nr) {
                    v[nr] = acc[mr][nr][j] + bias[nr * 16 + l15];
                    m = fmaxf(m, v[nr]);
                }
                #pragma unroll
                for (int d = 8; d >= 1; d >>= 1) m = fmaxf(m, __shfl_xor(m, d));
                float ssum = 0.f;
                #pragma unroll
                for (int nr = 0; nr < NR; ++nr) ssum += __expf(v[nr] - m);
                #pragma unroll
                for (int d = 8; d >= 1; d >>= 1) ssum += __shfl_xor(ssum, d);
                float lse = m + logf(ssum);
                if (row < NN) {
                    #pragma unroll
                    for (int nr = 0; nr < NR; ++nr)
                        ((float*)outp)[(size_t)row * 64 + nr * 16 + l15] = v[nr] - lse;
                }
            }
        }
    } else {
        #pragma unroll
        for (int mr = 0; mr < MR; ++mr) {
            #pragma unroll
            for (int nr = 0; nr < NR; ++nr) {
                int col = colbase + nr * 16 + l15;
                float bv = bias[col];
                #pragma unroll
                for (int j = 0; j < 4; ++j) {
                    int row = row0 + rowbase + mr * 16 + r4 + j;
                    if (row < NN) {
                        float v = acc[mr][nr][j] + bv;
                        if (RELU) v = fmaxf(v, 0.f);
                        if (OUTBF) ((unsigned short*)outp)[(size_t)row * BN + col] = f2bf(v);
                        else       ((float*)outp)[(size_t)row * BN + col] = v;
                    }
                }
            }
        }
    }
}

// ---------------- launch ----------------
extern "C" void kernel_launch(void* const* d_in, const int* in_sizes, int n_in,
                              void* d_out, int out_size, void* d_ws, size_t ws_size,
                              hipStream_t stream) {
    const float* x   = (const float*)d_in[0];
    const int* edges = (const int*)d_in[1];
    const float* W1l = (const float*)d_in[2];
    const float* b1  = (const float*)d_in[3];
    const float* W1r = (const float*)d_in[4];
    const float* W2l = (const float*)d_in[5];
    const float* b2  = (const float*)d_in[6];
    const float* W2r = (const float*)d_in[7];
    float* out = (float*)d_out;

    const int* src = edges;            // edge_index[0]
    const int* dst = edges + NE;       // edge_index[1]

    char* ws = (char*)d_ws;
    size_t o = 0;
    auto alloc = [&](size_t bytes) -> void* {
        void* p = ws + o;
        o = (o + bytes + 255) & ~(size_t)255;
        return p;
    };
    int* deg  = (int*)alloc((size_t)NN * 4);
    int* offs = (int*)alloc((size_t)NN * 4);
    int* bsum = (int*)alloc((size_t)SCAN_NBLK * 4);
    int* csr  = (int*)alloc((size_t)NE * 4);
    int* rank = (int*)alloc((size_t)NE * 4);
    unsigned short* xb    = (unsigned short*)alloc((size_t)NN * 128 * 2);
    unsigned short* meanb = (unsigned short*)alloc((size_t)NN * 128 * 2);
    unsigned short* hb    = (unsigned short*)alloc((size_t)NN * 128 * 2);
    unsigned short* Wt1l  = (unsigned short*)alloc(128 * 128 * 2);
    unsigned short* Wt1r  = (unsigned short*)alloc(128 * 128 * 2);
    unsigned short* Wt2l  = (unsigned short*)alloc(64 * 128 * 2);
    unsigned short* Wt2r  = (unsigned short*)alloc(64 * 128 * 2);

    hipMemsetAsync(deg, 0, (size_t)NN * 4, stream);

    // conversions
    k_cvt_x<<<2048, 256, 0, stream>>>(x, xb, (long)NN * 128 / 8);
    k_cvt_w<<<(128 * 128 + 255) / 256, 256, 0, stream>>>(W1l, Wt1l, 128);
    k_cvt_w<<<(128 * 128 + 255) / 256, 256, 0, stream>>>(W1r, Wt1r, 128);
    k_cvt_w<<<(64 * 128 + 255) / 256, 256, 0, stream>>>(W2l, Wt2l, 64);
    k_cvt_w<<<(64 * 128 + 255) / 256, 256, 0, stream>>>(W2r, Wt2r, 64);

    // CSR build: rank -> scan -> place
    k_rank<<<(NE + 255) / 256, 256, 0, stream>>>(dst, deg, rank);
    k_block_scan<<<SCAN_NBLK, 256, 0, stream>>>(deg, offs, bsum);
    k_scan_sums<<<1, 128, 0, stream>>>(bsum);
    k_add_base<<<(NN + 255) / 256, 256, 0, stream>>>(offs, bsum);
    k_place<<<(NE + 255) / 256, 256, 0, stream>>>(src, dst, offs, rank, csr);

    const int GEMM_GRID = (NN + 127) / 128;   // 782
    // layer 1
    k_aggregate_bf<<<NN / 4, 256, 0, stream>>>(xb, csr, offs, deg, meanb);
    k_gemm_mfma<128, true, true, false><<<GEMM_GRID, 256, 0, stream>>>(meanb, xb, Wt1l, Wt1r, b1, hb);
    // layer 2 (log_softmax fused into GEMM epilogue)
    k_aggregate_bf<<<NN / 4, 256, 0, stream>>>(hb, csr, offs, deg, meanb);
    k_gemm_mfma<64, false, false, true><<<GEMM_GRID, 256, 0, stream>>>(meanb, hb, Wt2l, Wt2r, b2, out);
}

// Round 7
// 291.899 us; speedup vs baseline: 1.3453x; 1.0674x over previous
//
#include <hip/hip_runtime.h>
#include <math.h>

#define NN 100000
#define NE 1600000
#define NBK ((NN + 63) / 64)        // 1563 buckets of 64 nodes
#define BCAP 2048                   // per-bucket edge capacity (avg 1024, 32 sigma safe)

typedef __attribute__((ext_vector_type(8))) short bf16x8;   // 8 bf16 = 4 VGPR (MFMA A/B frag)
typedef __attribute__((ext_vector_type(8))) unsigned short ush8;
typedef __attribute__((ext_vector_type(4))) float f32x4;    // MFMA C/D frag

static __device__ __forceinline__ float b2f(unsigned short u) {
    return __uint_as_float(((unsigned int)u) << 16);
}
static __device__ __forceinline__ unsigned short f2bf(float f) {
    unsigned int u = __float_as_uint(f);
    u += 0x7fffu + ((u >> 16) & 1u);   // RNE
    return (unsigned short)(u >> 16);
}

// ---------------- conversions ----------------
__global__ __launch_bounds__(256)
void k_cvt_x(const float* __restrict__ in, unsigned short* __restrict__ outb, long total8) {
    long i = (long)blockIdx.x * 256 + threadIdx.x;
    long stride = (long)gridDim.x * 256;
    for (; i < total8; i += stride) {
        const float4* p = (const float4*)(in + i * 8);
        float4 a = p[0], b = p[1];
        ush8 r;
        r[0] = f2bf(a.x); r[1] = f2bf(a.y); r[2] = f2bf(a.z); r[3] = f2bf(a.w);
        r[4] = f2bf(b.x); r[5] = f2bf(b.y); r[6] = f2bf(b.z); r[7] = f2bf(b.w);
        *(ush8*)(outb + i * 8) = r;
    }
}

// W [128, N] f32 -> Wt [N, 128] bf16 (row-major over n)
__global__ __launch_bounds__(256)
void k_cvt_w(const float* __restrict__ W, unsigned short* __restrict__ Wt, int N) {
    int id = blockIdx.x * 256 + threadIdx.x;
    if (id < N * 128) {
        int n = id >> 7, k = id & 127;
        Wt[id] = f2bf(W[k * N + n]);
    }
}

// ---------------- edge bucketing: single atomic pass onto 1563 padded counters ----------------
// pairs[b*BCAP + slot] = src*64 | (dst&63)
__global__ __launch_bounds__(256)
void k_scatter(const int* __restrict__ src, const int* __restrict__ dst,
               int* __restrict__ cur, int* __restrict__ pairs) {
    int e = blockIdx.x * 256 + threadIdx.x;
    if (e >= NE) return;
    int d = dst[e];
    int s = src[e];
    int b = d >> 6;
    int p = atomicAdd(&cur[b * 16], 1);   // 64B-padded counter per bucket
    if (p < BCAP) pairs[(size_t)b * BCAP + p] = (s << 6) | (d & 63);
}

// ---------------- fused bucket aggregate: LDS counting-sort + gather + mean ----------------
// One block per bucket (64 nodes). Stage edges in LDS, histogram 64 node-counters
// (= degrees), wave-scan, LDS counting sort -> per-bucket CSR in LDS, then the
// 16-lane-group gather (4 edges/iter, unroll 2) identical in structure to the
// proven k_aggregate_bf.
__global__ __launch_bounds__(256)
void k_bucket_agg(const unsigned short* __restrict__ feat, const int* __restrict__ pairs,
                  const int* __restrict__ cur, unsigned short* __restrict__ outmean) {
    __shared__ int stage[BCAP];
    __shared__ int lcsr[BCAP];
    __shared__ int lhist[64], loffs[64], lpos[64];

    const int b = blockIdx.x;
    const int tid = threadIdx.x;
    int cnt = cur[b * 16];
    if (cnt > BCAP) cnt = BCAP;
    const int* __restrict__ pb = pairs + (size_t)b * BCAP;

    for (int i = tid; i < cnt; i += 256) stage[i] = pb[i];
    if (tid < 64) lhist[tid] = 0;
    __syncthreads();

    for (int i = tid; i < cnt; i += 256) atomicAdd(&lhist[stage[i] & 63], 1);
    __syncthreads();

    if (tid < 64) {   // wave 0: exclusive scan of 64 counters
        int v = lhist[tid];
        int inc = v;
        #pragma unroll
        for (int d = 1; d < 64; d <<= 1) {
            int t = __shfl_up(inc, d);
            if (tid >= d) inc += t;
        }
        loffs[tid] = inc - v;
        lpos[tid]  = inc - v;
    }
    __syncthreads();

    for (int i = tid; i < cnt; i += 256) {
        int p = stage[i];
        int slot = atomicAdd(&lpos[p & 63], 1);
        lcsr[slot] = p >> 6;
    }
    __syncthreads();

    // gather: wave w handles nodes n = w, w+4, ...
    const int wid = tid >> 6, lane = tid & 63;
    const int q = lane >> 4, l4 = lane & 15;
    const ush8* __restrict__ f8 = (const ush8*)feat;

    for (int n = wid; n < 64; n += 4) {
        int node = b * 64 + n;
        if (node >= NN) break;
        int off = loffs[n];
        int dg  = lhist[n];
        float acc[8];
        #pragma unroll
        for (int i = 0; i < 8; ++i) acc[i] = 0.f;
        int j = 0;
        for (; j + 8 <= dg; j += 8) {
            int e0 = lcsr[off + j + q];
            int e1 = lcsr[off + j + 4 + q];
            ush8 v0 = f8[(size_t)e0 * 16 + l4];
            ush8 v1 = f8[(size_t)e1 * 16 + l4];
            #pragma unroll
            for (int i = 0; i < 8; ++i) acc[i] += b2f(v0[i]) + b2f(v1[i]);
        }
        for (; j + 4 <= dg; j += 4) {
            int e0 = lcsr[off + j + q];
            ush8 v0 = f8[(size_t)e0 * 16 + l4];
            #pragma unroll
            for (int i = 0; i < 8; ++i) acc[i] += b2f(v0[i]);
        }
        int rem = dg - j;
        if (q < rem) {
            int e0 = lcsr[off + j + q];
            ush8 v0 = f8[(size_t)e0 * 16 + l4];
            #pragma unroll
            for (int i = 0; i < 8; ++i) acc[i] += b2f(v0[i]);
        }
        #pragma unroll
        for (int i = 0; i < 8; ++i) {
            acc[i] += __shfl_xor(acc[i], 16);
            acc[i] += __shfl_xor(acc[i], 32);
        }
        if (q == 0) {
            float inv = 1.0f / (float)(dg > 0 ? dg : 1);
            ush8 r;
            #pragma unroll
            for (int i = 0; i < 8; ++i) r[i] = f2bf(acc[i] * inv);
            ((ush8*)outmean)[(size_t)node * 16 + l4] = r;
        }
    }
}

// ---------------- MFMA dual GEMM: out = Am@Wl + Ax@Wr + bias (+relu / +log_softmax) ----------------
// A: [NN,128] bf16. Wt: [BN,128] bf16 (pre-transposed). Block: 128 rows x BN cols, 4 waves.
template <int BN, bool RELU, bool OUTBF, bool LSM>
__global__ __launch_bounds__(256)
void k_gemm_mfma(const unsigned short* __restrict__ Am, const unsigned short* __restrict__ Ax,
                 const unsigned short* __restrict__ Wtl, const unsigned short* __restrict__ Wtr,
                 const float* __restrict__ bias, void* __restrict__ outp) {
    constexpr int BM = 128;
    constexpr int WAVES_N = BN / 64;          // 2 (BN=128) or 1 (BN=64)
    constexpr int WAVES_M = 4 / WAVES_N;      // 2 or 4
    constexpr int MR = BM / (WAVES_M * 16);   // 4 or 2
    constexpr int NR = 4;                     // 64 cols per wave
    __shared__ __align__(16) short As[BM * 40];   // 80B row stride -> uniform banks
    __shared__ __align__(16) short Ws[BN * 40];

    const int tid = threadIdx.x;
    const int wave = tid >> 6, lane = tid & 63;
    const int l15 = lane & 15, kg = lane >> 4;
    const int wc = wave % WAVES_N, wr = wave / WAVES_N;
    const int rowbase = wr * MR * 16;
    const int colbase = wc * 64;
    const int row0 = blockIdx.x * BM;

    f32x4 acc[MR][NR];
    #pragma unroll
    for (int mr = 0; mr < MR; ++mr)
        #pragma unroll
        for (int nr = 0; nr < NR; ++nr) acc[mr][nr] = (f32x4){0.f, 0.f, 0.f, 0.f};

    for (int s = 0; s < 2; ++s) {
        const unsigned short* __restrict__ A  = s ? Ax : Am;
        const unsigned short* __restrict__ Wt = s ? Wtr : Wtl;
        for (int kc = 0; kc < 128; kc += 32) {
            __syncthreads();
            #pragma unroll
            for (int i = 0; i < (BM * 4) / 256; ++i) {
                int c = tid + 256 * i; int r = c >> 2, g = c & 3;
                ush8 v = {0, 0, 0, 0, 0, 0, 0, 0};
                int grow = row0 + r;
                if (grow < NN) v = *(const ush8*)&A[(size_t)grow * 128 + kc + g * 8];
                *(ush8*)&As[r * 40 + g * 8] = v;
            }
            #pragma unroll
            for (int i = 0; i < (BN * 4) / 256; ++i) {
                int c = tid + 256 * i; int n = c >> 2, g = c & 3;
                *(ush8*)&Ws[n * 40 + g * 8] = *(const ush8*)&Wt[n * 128 + kc + g * 8];
            }
            __syncthreads();
            bf16x8 af[MR], bfr[NR];
            #pragma unroll
            for (int mr = 0; mr < MR; ++mr)
                af[mr] = *(const bf16x8*)&As[(rowbase + mr * 16 + l15) * 40 + kg * 8];
            #pragma unroll
            for (int nr = 0; nr < NR; ++nr)
                bfr[nr] = *(const bf16x8*)&Ws[(colbase + nr * 16 + l15) * 40 + kg * 8];
            #pragma unroll
            for (int mr = 0; mr < MR; ++mr)
                #pragma unroll
                for (int nr = 0; nr < NR; ++nr)
                    acc[mr][nr] = __builtin_amdgcn_mfma_f32_16x16x32_bf16(
                        af[mr], bfr[nr], acc[mr][nr], 0, 0, 0);
        }
    }
    // epilogue
    const int r4 = kg * 4;
    if (LSM) {
        // BN==64: each 16-lane group holds one full 64-col row per (mr,j).
        #pragma unroll
        for (int mr = 0; mr < MR; ++mr) {
            #pragma unroll
            for (int j = 0; j < 4; ++j) {
                int row = row0 + rowbase + mr * 16 + r4 + j;
                float v[NR];
                float m = -1e30f;
                #pragma unroll
                for (int nr = 0; nr < NR; ++nr) {
                    v[nr] = acc[mr][nr][j] + bias[nr * 16 + l15];
                    m = fmaxf(m, v[nr]);
                }
                #pragma unroll
                for (int d = 8; d >= 1; d >>= 1) m = fmaxf(m, __shfl_xor(m, d));
                float ssum = 0.f;
                #pragma unroll
                for (int nr = 0; nr < NR; ++nr) ssum += __expf(v[nr] - m);
                #pragma unroll
                for (int d = 8; d >= 1; d >>= 1) ssum += __shfl_xor(ssum, d);
                float lse = m + logf(ssum);
                if (row < NN) {
                    #pragma unroll
                    for (int nr = 0; nr < NR; ++nr)
                        ((float*)outp)[(size_t)row * 64 + nr * 16 + l15] = v[nr] - lse;
                }
            }
        }
    } else {
        #pragma unroll
        for (int mr = 0; mr < MR; ++mr) {
            #pragma unroll
            for (int nr = 0; nr < NR; ++nr) {
                int col = colbase + nr * 16 + l15;
                float bv = bias[col];
                #pragma unroll
                for (int j = 0; j < 4; ++j) {
                    int row = row0 + rowbase + mr * 16 + r4 + j;
                    if (row < NN) {
                        float v = acc[mr][nr][j] + bv;
                        if (RELU) v = fmaxf(v, 0.f);
                        if (OUTBF) ((unsigned short*)outp)[(size_t)row * BN + col] = f2bf(v);
                        else       ((float*)outp)[(size_t)row * BN + col] = v;
                    }
                }
            }
        }
    }
}

// ---------------- launch ----------------
extern "C" void kernel_launch(void* const* d_in, const int* in_sizes, int n_in,
                              void* d_out, int out_size, void* d_ws, size_t ws_size,
                              hipStream_t stream) {
    const float* x   = (const float*)d_in[0];
    const int* edges = (const int*)d_in[1];
    const float* W1l = (const float*)d_in[2];
    const float* b1  = (const float*)d_in[3];
    const float* W1r = (const float*)d_in[4];
    const float* W2l = (const float*)d_in[5];
    const float* b2  = (const float*)d_in[6];
    const float* W2r = (const float*)d_in[7];
    float* out = (float*)d_out;

    const int* src = edges;            // edge_index[0]
    const int* dst = edges + NE;       // edge_index[1]

    char* ws = (char*)d_ws;
    size_t o = 0;
    auto alloc = [&](size_t bytes) -> void* {
        void* p = ws + o;
        o = (o + bytes + 255) & ~(size_t)255;
        return p;
    };
    int* cur   = (int*)alloc((size_t)NBK * 16 * 4);        // 64B-padded bucket counters
    int* pairs = (int*)alloc((size_t)NBK * BCAP * 4);      // 12.8 MB bucketed edges
    unsigned short* xb    = (unsigned short*)alloc((size_t)NN * 128 * 2);
    unsigned short* meanb = (unsigned short*)alloc((size_t)NN * 128 * 2);
    unsigned short* hb    = (unsigned short*)alloc((size_t)NN * 128 * 2);
    unsigned short* Wt1l  = (unsigned short*)alloc(128 * 128 * 2);
    unsigned short* Wt1r  = (unsigned short*)alloc(128 * 128 * 2);
    unsigned short* Wt2l  = (unsigned short*)alloc(64 * 128 * 2);
    unsigned short* Wt2r  = (unsigned short*)alloc(64 * 128 * 2);

    hipMemsetAsync(cur, 0, (size_t)NBK * 16 * 4, stream);

    // conversions
    k_cvt_x<<<2048, 256, 0, stream>>>(x, xb, (long)NN * 128 / 8);
    k_cvt_w<<<(128 * 128 + 255) / 256, 256, 0, stream>>>(W1l, Wt1l, 128);
    k_cvt_w<<<(128 * 128 + 255) / 256, 256, 0, stream>>>(W1r, Wt1r, 128);
    k_cvt_w<<<(64 * 128 + 255) / 256, 256, 0, stream>>>(W2l, Wt2l, 64);
    k_cvt_w<<<(64 * 128 + 255) / 256, 256, 0, stream>>>(W2r, Wt2r, 64);

    // bucket the edges (single atomic pass)
    k_scatter<<<(NE + 255) / 256, 256, 0, stream>>>(src, dst, cur, pairs);

    const int GEMM_GRID = (NN + 127) / 128;   // 782
    // layer 1
    k_bucket_agg<<<NBK, 256, 0, stream>>>(xb, pairs, cur, meanb);
    k_gemm_mfma<128, true, true, false><<<GEMM_GRID, 256, 0, stream>>>(meanb, xb, Wt1l, Wt1r, b1, hb);
    // layer 2 (log_softmax fused into GEMM epilogue)
    k_bucket_agg<<<NBK, 256, 0, stream>>>(hb, pairs, cur, meanb);
    k_gemm_mfma<64, false, false, true><<<GEMM_GRID, 256, 0, stream>>>(meanb, hb, Wt2l, Wt2r, b2, out);
}

// Round 8
// 286.523 us; speedup vs baseline: 1.3706x; 1.0188x over previous
//
#include <hip/hip_runtime.h>
#include <math.h>

#define NN 100000
#define NE 1600000
#define NBK ((NN + 63) / 64)        // 1563 buckets of 64 nodes
#define NSH 8                       // counter shards per bucket
#define SCAP 256                    // per-shard edge capacity (avg 128)
#define BCAP (NSH * SCAP)           // 2048 per bucket

typedef __attribute__((ext_vector_type(8))) short bf16x8;   // 8 bf16 = 4 VGPR (MFMA A/B frag)
typedef __attribute__((ext_vector_type(8))) unsigned short ush8;
typedef __attribute__((ext_vector_type(4))) float f32x4;    // MFMA C/D frag

static __device__ __forceinline__ float b2f(unsigned short u) {
    return __uint_as_float(((unsigned int)u) << 16);
}
static __device__ __forceinline__ unsigned short f2bf(float f) {
    unsigned int u = __float_as_uint(f);
    u += 0x7fffu + ((u >> 16) & 1u);   // RNE
    return (unsigned short)(u >> 16);
}

// ---------------- conversions ----------------
__global__ __launch_bounds__(256)
void k_cvt_x(const float* __restrict__ in, unsigned short* __restrict__ outb, long total8) {
    long i = (long)blockIdx.x * 256 + threadIdx.x;
    long stride = (long)gridDim.x * 256;
    for (; i < total8; i += stride) {
        const float4* p = (const float4*)(in + i * 8);
        float4 a = p[0], b = p[1];
        ush8 r;
        r[0] = f2bf(a.x); r[1] = f2bf(a.y); r[2] = f2bf(a.z); r[3] = f2bf(a.w);
        r[4] = f2bf(b.x); r[5] = f2bf(b.y); r[6] = f2bf(b.z); r[7] = f2bf(b.w);
        *(ush8*)(outb + i * 8) = r;
    }
}

// W [128, N] f32 -> Wt [N, 128] bf16 (row-major over n)
__global__ __launch_bounds__(256)
void k_cvt_w(const float* __restrict__ W, unsigned short* __restrict__ Wt, int N) {
    int id = blockIdx.x * 256 + threadIdx.x;
    if (id < N * 128) {
        int n = id >> 7, k = id & 127;
        Wt[id] = f2bf(W[k * N + n]);
    }
}

// ---------------- edge bucketing: 8-way sharded counters (contention /8) ----------------
// pairs[(b*NSH+s)*SCAP + slot] = src*64 | (dst&63)
__global__ __launch_bounds__(256)
void k_scatter(const int* __restrict__ src, const int* __restrict__ dst,
               int* __restrict__ cur, int* __restrict__ pairs) {
    int e = blockIdx.x * 256 + threadIdx.x;
    if (e >= NE) return;
    int sh = blockIdx.x & (NSH - 1);
    int d = dst[e];
    int s = src[e];
    int b = d >> 6;
    int ci = (b * NSH + sh);
    int p = atomicAdd(&cur[ci * 16], 1);   // 64B-padded counter per (bucket,shard)
    if (p < SCAP)
        __builtin_nontemporal_store((s << 6) | (d & 63), &pairs[(size_t)ci * SCAP + p]);
}

// ---------------- fused bucket aggregate: LDS counting-sort + gather + mean ----------------
// One block per bucket (64 nodes). Stage 8 shard segments in LDS, histogram 64
// node-counters (= degrees), wave-scan, LDS counting sort -> per-bucket CSR in
// LDS, then the 16-lane-group gather (4 edges/iter, unroll 2).
__global__ __launch_bounds__(256)
void k_bucket_agg(const unsigned short* __restrict__ feat, const int* __restrict__ pairs,
                  const int* __restrict__ cur, unsigned short* __restrict__ outmean) {
    __shared__ int stage[BCAP];
    __shared__ int lcsr[BCAP];
    __shared__ int lhist[64], loffs[64], lpos[64];
    __shared__ int scnt[NSH], sbase[NSH + 1];

    const int b = blockIdx.x;
    const int tid = threadIdx.x;

    if (tid < NSH) {
        int c = cur[(b * NSH + tid) * 16];
        scnt[tid] = c > SCAP ? SCAP : c;
    }
    if (tid < 64) lhist[tid] = 0;
    __syncthreads();
    if (tid == 0) {
        int t = 0;
        #pragma unroll
        for (int s = 0; s < NSH; ++s) { sbase[s] = t; t += scnt[s]; }
        sbase[NSH] = t;
    }
    __syncthreads();

    #pragma unroll
    for (int s = 0; s < NSH; ++s) {
        int c = scnt[s], bs = sbase[s];
        const int* __restrict__ pp = pairs + (size_t)(b * NSH + s) * SCAP;
        for (int i = tid; i < c; i += 256) stage[bs + i] = pp[i];
    }
    __syncthreads();
    const int cnt = sbase[NSH];

    for (int i = tid; i < cnt; i += 256) atomicAdd(&lhist[stage[i] & 63], 1);
    __syncthreads();

    if (tid < 64) {   // wave 0: exclusive scan of 64 counters
        int v = lhist[tid];
        int inc = v;
        #pragma unroll
        for (int d = 1; d < 64; d <<= 1) {
            int t = __shfl_up(inc, d);
            if (tid >= d) inc += t;
        }
        loffs[tid] = inc - v;
        lpos[tid]  = inc - v;
    }
    __syncthreads();

    for (int i = tid; i < cnt; i += 256) {
        int p = stage[i];
        int slot = atomicAdd(&lpos[p & 63], 1);
        lcsr[slot] = p >> 6;
    }
    __syncthreads();

    // gather: wave w handles nodes n = w, w+4, ...
    const int wid = tid >> 6, lane = tid & 63;
    const int q = lane >> 4, l4 = lane & 15;
    const ush8* __restrict__ f8 = (const ush8*)feat;

    for (int n = wid; n < 64; n += 4) {
        int node = b * 64 + n;
        if (node >= NN) break;
        int off = loffs[n];
        int dg  = lhist[n];
        float acc[8];
        #pragma unroll
        for (int i = 0; i < 8; ++i) acc[i] = 0.f;
        int j = 0;
        for (; j + 8 <= dg; j += 8) {
            int e0 = lcsr[off + j + q];
            int e1 = lcsr[off + j + 4 + q];
            ush8 v0 = f8[(size_t)e0 * 16 + l4];
            ush8 v1 = f8[(size_t)e1 * 16 + l4];
            #pragma unroll
            for (int i = 0; i < 8; ++i) acc[i] += b2f(v0[i]) + b2f(v1[i]);
        }
        for (; j + 4 <= dg; j += 4) {
            int e0 = lcsr[off + j + q];
            ush8 v0 = f8[(size_t)e0 * 16 + l4];
            #pragma unroll
            for (int i = 0; i < 8; ++i) acc[i] += b2f(v0[i]);
        }
        int rem = dg - j;
        if (q < rem) {
            int e0 = lcsr[off + j + q];
            ush8 v0 = f8[(size_t)e0 * 16 + l4];
            #pragma unroll
            for (int i = 0; i < 8; ++i) acc[i] += b2f(v0[i]);
        }
        #pragma unroll
        for (int i = 0; i < 8; ++i) {
            acc[i] += __shfl_xor(acc[i], 16);
            acc[i] += __shfl_xor(acc[i], 32);
        }
        if (q == 0) {
            float inv = 1.0f / (float)(dg > 0 ? dg : 1);
            ush8 r;
            #pragma unroll
            for (int i = 0; i < 8; ++i) r[i] = f2bf(acc[i] * inv);
            ((ush8*)outmean)[(size_t)node * 16 + l4] = r;
        }
    }
}

// ---------------- MFMA dual GEMM: out = Am@Wl + Ax@Wr + bias (+relu / +log_softmax) ----------------
// A: [NN,128] bf16. Wt: [BN,128] bf16 (pre-transposed). Block: 128 rows x BN cols, 4 waves.
template <int BN, bool RELU, bool OUTBF, bool LSM>
__global__ __launch_bounds__(256)
void k_gemm_mfma(const unsigned short* __restrict__ Am, const unsigned short* __restrict__ Ax,
                 const unsigned short* __restrict__ Wtl, const unsigned short* __restrict__ Wtr,
                 const float* __restrict__ bias, void* __restrict__ outp) {
    constexpr int BM = 128;
    constexpr int WAVES_N = BN / 64;          // 2 (BN=128) or 1 (BN=64)
    constexpr int WAVES_M = 4 / WAVES_N;      // 2 or 4
    constexpr int MR = BM / (WAVES_M * 16);   // 4 or 2
    constexpr int NR = 4;                     // 64 cols per wave
    __shared__ __align__(16) short As[BM * 40];   // 80B row stride -> uniform banks
    __shared__ __align__(16) short Ws[BN * 40];

    const int tid = threadIdx.x;
    const int wave = tid >> 6, lane = tid & 63;
    const int l15 = lane & 15, kg = lane >> 4;
    const int wc = wave % WAVES_N, wr = wave / WAVES_N;
    const int rowbase = wr * MR * 16;
    const int colbase = wc * 64;
    const int row0 = blockIdx.x * BM;

    f32x4 acc[MR][NR];
    #pragma unroll
    for (int mr = 0; mr < MR; ++mr)
        #pragma unroll
        for (int nr = 0; nr < NR; ++nr) acc[mr][nr] = (f32x4){0.f, 0.f, 0.f, 0.f};

    for (int s = 0; s < 2; ++s) {
        const unsigned short* __restrict__ A  = s ? Ax : Am;
        const unsigned short* __restrict__ Wt = s ? Wtr : Wtl;
        for (int kc = 0; kc < 128; kc += 32) {
            __syncthreads();
            #pragma unroll
            for (int i = 0; i < (BM * 4) / 256; ++i) {
                int c = tid + 256 * i; int r = c >> 2, g = c & 3;
                ush8 v = {0, 0, 0, 0, 0, 0, 0, 0};
                int grow = row0 + r;
                if (grow < NN) v = *(const ush8*)&A[(size_t)grow * 128 + kc + g * 8];
                *(ush8*)&As[r * 40 + g * 8] = v;
            }
            #pragma unroll
            for (int i = 0; i < (BN * 4) / 256; ++i) {
                int c = tid + 256 * i; int n = c >> 2, g = c & 3;
                *(ush8*)&Ws[n * 40 + g * 8] = *(const ush8*)&Wt[n * 128 + kc + g * 8];
            }
            __syncthreads();
            bf16x8 af[MR], bfr[NR];
            #pragma unroll
            for (int mr = 0; mr < MR; ++mr)
                af[mr] = *(const bf16x8*)&As[(rowbase + mr * 16 + l15) * 40 + kg * 8];
            #pragma unroll
            for (int nr = 0; nr < NR; ++nr)
                bfr[nr] = *(const bf16x8*)&Ws[(colbase + nr * 16 + l15) * 40 + kg * 8];
            #pragma unroll
            for (int mr = 0; mr < MR; ++mr)
                #pragma unroll
                for (int nr = 0; nr < NR; ++nr)
                    acc[mr][nr] = __builtin_amdgcn_mfma_f32_16x16x32_bf16(
                        af[mr], bfr[nr], acc[mr][nr], 0, 0, 0);
        }
    }
    // epilogue
    const int r4 = kg * 4;
    if (LSM) {
        // BN==64: each 16-lane group holds one full 64-col row per (mr,j).
        #pragma unroll
        for (int mr = 0; mr < MR; ++mr) {
            #pragma unroll
            for (int j = 0; j < 4; ++j) {
                int row = row0 + rowbase + mr * 16 + r4 + j;
                float v[NR];
                float m = -1e30f;
                #pragma unroll
                for (int nr = 0; nr < NR; ++nr) {
                    v[nr] = acc[mr][nr][j] + bias[nr * 16 + l15];
                    m = fmaxf(m, v[nr]);
                }
                #pragma unroll
                for (int d = 8; d >= 1; d >>= 1) m = fmaxf(m, __shfl_xor(m, d));
                float ssum = 0.f;
                #pragma unroll
                for (int nr = 0; nr < NR; ++nr) ssum += __expf(v[nr] - m);
                #pragma unroll
                for (int d = 8; d >= 1; d >>= 1) ssum += __shfl_xor(ssum, d);
                float lse = m + logf(ssum);
                if (row < NN) {
                    #pragma unroll
                    for (int nr = 0; nr < NR; ++nr)
                        ((float*)outp)[(size_t)row * 64 + nr * 16 + l15] = v[nr] - lse;
                }
            }
        }
    } else {
        #pragma unroll
        for (int mr = 0; mr < MR; ++mr) {
            #pragma unroll
            for (int nr = 0; nr < NR; ++nr) {
                int col = colbase + nr * 16 + l15;
                float bv = bias[col];
                #pragma unroll
                for (int j = 0; j < 4; ++j) {
                    int row = row0 + rowbase + mr * 16 + r4 + j;
                    if (row < NN) {
                        float v = acc[mr][nr][j] + bv;
                        if (RELU) v = fmaxf(v, 0.f);
                        if (OUTBF) ((unsigned short*)outp)[(size_t)row * BN + col] = f2bf(v);
                        else       ((float*)outp)[(size_t)row * BN + col] = v;
                    }
                }
            }
        }
    }
}

// ---------------- launch ----------------
extern "C" void kernel_launch(void* const* d_in, const int* in_sizes, int n_in,
                              void* d_out, int out_size, void* d_ws, size_t ws_size,
                              hipStream_t stream) {
    const float* x   = (const float*)d_in[0];
    const int* edges = (const int*)d_in[1];
    const float* W1l = (const float*)d_in[2];
    const float* b1  = (const float*)d_in[3];
    const float* W1r = (const float*)d_in[4];
    const float* W2l = (const float*)d_in[5];
    const float* b2  = (const float*)d_in[6];
    const float* W2r = (const float*)d_in[7];
    float* out = (float*)d_out;

    const int* src = edges;            // edge_index[0]
    const int* dst = edges + NE;       // edge_index[1]

    char* ws = (char*)d_ws;
    size_t o = 0;
    auto alloc = [&](size_t bytes) -> void* {
        void* p = ws + o;
        o = (o + bytes + 255) & ~(size_t)255;
        return p;
    };
    int* cur   = (int*)alloc((size_t)NBK * NSH * 16 * 4);  // 64B-padded sharded counters
    int* pairs = (int*)alloc((size_t)NBK * BCAP * 4);      // 12.8 MB bucketed edges
    unsigned short* xb    = (unsigned short*)alloc((size_t)NN * 128 * 2);
    unsigned short* meanb = (unsigned short*)alloc((size_t)NN * 128 * 2);
    unsigned short* hb    = (unsigned short*)alloc((size_t)NN * 128 * 2);
    unsigned short* Wt1l  = (unsigned short*)alloc(128 * 128 * 2);
    unsigned short* Wt1r  = (unsigned short*)alloc(128 * 128 * 2);
    unsigned short* Wt2l  = (unsigned short*)alloc(64 * 128 * 2);
    unsigned short* Wt2r  = (unsigned short*)alloc(64 * 128 * 2);

    hipMemsetAsync(cur, 0, (size_t)NBK * NSH * 16 * 4, stream);

    // conversions
    k_cvt_x<<<2048, 256, 0, stream>>>(x, xb, (long)NN * 128 / 8);
    k_cvt_w<<<(128 * 128 + 255) / 256, 256, 0, stream>>>(W1l, Wt1l, 128);
    k_cvt_w<<<(128 * 128 + 255) / 256, 256, 0, stream>>>(W1r, Wt1r, 128);
    k_cvt_w<<<(64 * 128 + 255) / 256, 256, 0, stream>>>(W2l, Wt2l, 64);
    k_cvt_w<<<(64 * 128 + 255) / 256, 256, 0, stream>>>(W2r, Wt2r, 64);

    // bucket the edges (single sharded atomic pass)
    k_scatter<<<(NE + 255) / 256, 256, 0, stream>>>(src, dst, cur, pairs);

    const int GEMM_GRID = (NN + 127) / 128;   // 782
    // layer 1
    k_bucket_agg<<<NBK, 256, 0, stream>>>(xb, pairs, cur, meanb);
    k_gemm_mfma<128, true, true, false><<<GEMM_GRID, 256, 0, stream>>>(meanb, xb, Wt1l, Wt1r, b1, hb);
    // layer 2 (log_softmax fused into GEMM epilogue)
    k_bucket_agg<<<NBK, 256, 0, stream>>>(hb, pairs, cur, meanb);
    k_gemm_mfma<64, false, false, true><<<GEMM_GRID, 256, 0, stream>>>(meanb, hb, Wt2l, Wt2r, b2, out);
}

// Round 9
// 226.104 us; speedup vs baseline: 1.7368x; 1.2672x over previous
//
#include <hip/hip_runtime.h>
#include <math.h>

#define NN 100000
#define NE 1600000
#define SBN 512                      // nodes per super-bucket
#define NSB ((NN + SBN - 1) / SBN)   // 196 super-buckets
#define SBCAP 10240                  // per-super-bucket edge capacity (mean 8192)
#define EPB 8192                     // edges per binA block
#define NBA ((NE + EPB - 1) / EPB)   // 196 binA blocks

typedef __attribute__((ext_vector_type(8))) short bf16x8;   // 8 bf16 = 4 VGPR (MFMA A/B frag)
typedef __attribute__((ext_vector_type(8))) unsigned short ush8;
typedef __attribute__((ext_vector_type(4))) float f32x4;    // MFMA C/D frag

static __device__ __forceinline__ float b2f(unsigned short u) {
    return __uint_as_float(((unsigned int)u) << 16);
}
static __device__ __forceinline__ unsigned short f2bf(float f) {
    unsigned int u = __float_as_uint(f);
    u += 0x7fffu + ((u >> 16) & 1u);   // RNE
    return (unsigned short)(u >> 16);
}

// ---------------- conversions ----------------
__global__ __launch_bounds__(256)
void k_cvt_x(const float* __restrict__ in, unsigned short* __restrict__ outb, long total8) {
    long i = (long)blockIdx.x * 256 + threadIdx.x;
    long stride = (long)gridDim.x * 256;
    for (; i < total8; i += stride) {
        const float4* p = (const float4*)(in + i * 8);
        float4 a = p[0], b = p[1];
        ush8 r;
        r[0] = f2bf(a.x); r[1] = f2bf(a.y); r[2] = f2bf(a.z); r[3] = f2bf(a.w);
        r[4] = f2bf(b.x); r[5] = f2bf(b.y); r[6] = f2bf(b.z); r[7] = f2bf(b.w);
        *(ush8*)(outb + i * 8) = r;
    }
}

// W [128, N] f32 -> Wt [N, 128] bf16 (row-major over n)
__global__ __launch_bounds__(256)
void k_cvt_w(const float* __restrict__ W, unsigned short* __restrict__ Wt, int N) {
    int id = blockIdx.x * 256 + threadIdx.x;
    if (id < N * 128) {
        int n = id >> 7, k = id & 127;
        Wt[id] = f2bf(W[k * N + n]);
    }
}

// ---------------- pass A: LDS-binned counting sort into 196 super-buckets ----------------
// Coalesced chunk writes; ~196 global atomics per block (one per bin).
__global__ __launch_bounds__(1024)
void k_binA(const int* __restrict__ src, const int* __restrict__ dst,
            int* __restrict__ gcnt, int* __restrict__ pairs) {
    __shared__ int lsort[EPB];        // 32 KB
    __shared__ int lhist[256];
    __shared__ int lofs[256];         // exclusive offsets (immutable copy)
    __shared__ int lpos[NSB];
    __shared__ int gbase[NSB];
    const int tid = threadIdx.x;
    const int base = blockIdx.x * EPB;
    const int cnt = min(EPB, NE - base);

    int v[8], bn[8];
    #pragma unroll
    for (int k = 0; k < 8; ++k) {
        int i = k * 1024 + tid;
        if (i < cnt) {
            int d = dst[base + i], s = src[base + i];
            v[k] = (s << 9) | (d & 511);
            bn[k] = d >> 9;
        } else bn[k] = -1;
    }
    if (tid < 256) lhist[tid] = 0;
    __syncthreads();
    #pragma unroll
    for (int k = 0; k < 8; ++k) if (bn[k] >= 0) atomicAdd(&lhist[bn[k]], 1);
    __syncthreads();
    if (tid < 256) lofs[tid] = lhist[tid];
    __syncthreads();
    for (int d = 1; d < 256; d <<= 1) {
        int u = (tid < 256 && tid >= d) ? lofs[tid - d] : 0;
        __syncthreads();
        if (tid < 256) lofs[tid] += u;
        __syncthreads();
    }
    if (tid < 256) lofs[tid] -= lhist[tid];   // inclusive -> exclusive
    __syncthreads();
    if (tid < NSB) {
        lpos[tid] = lofs[tid];
        gbase[tid] = atomicAdd(&gcnt[tid], lhist[tid]);
    }
    __syncthreads();
    #pragma unroll
    for (int k = 0; k < 8; ++k) if (bn[k] >= 0) {
        int slot = atomicAdd(&lpos[bn[k]], 1);
        lsort[slot] = v[k];
    }
    __syncthreads();
    // coalesced writeout: binary-search the bin for each sorted index
    for (int i = tid; i < cnt; i += 1024) {
        int lo = 0, hi = NSB - 1;
        while (lo < hi) { int mid = (lo + hi + 1) >> 1; if (lofs[mid] <= i) lo = mid; else hi = mid - 1; }
        int off = gbase[lo] + (i - lofs[lo]);
        if (off < SBCAP)
            __builtin_nontemporal_store(lsort[i], &pairs[(size_t)lo * SBCAP + off]);
    }
}

// ---------------- pass B: per-super-bucket sort -> CSR (in place), deg/offs ----------------
__global__ __launch_bounds__(1024)
void k_sortB(const int* __restrict__ gcnt, int* __restrict__ pairs,
             int* __restrict__ offs, int* __restrict__ deg) {
    __shared__ int lstage[SBCAP];     // 40 KB
    __shared__ int lhist[SBN], lscan[SBN], lpos[SBN];
    const int sb = blockIdx.x, tid = threadIdx.x;
    const int cnt = min(gcnt[sb], SBCAP);
    int* __restrict__ region = pairs + (size_t)sb * SBCAP;

    for (int i = tid; i < cnt; i += 1024) lstage[i] = region[i];
    if (tid < SBN) lhist[tid] = 0;
    __syncthreads();
    for (int i = tid; i < cnt; i += 1024) atomicAdd(&lhist[lstage[i] & 511], 1);
    __syncthreads();
    if (tid < SBN) lscan[tid] = lhist[tid];
    __syncthreads();
    for (int d = 1; d < SBN; d <<= 1) {
        int u = (tid < SBN && tid >= d) ? lscan[tid - d] : 0;
        __syncthreads();
        if (tid < SBN) lscan[tid] += u;
        __syncthreads();
    }
    if (tid < SBN) {
        int ex = lscan[tid] - lhist[tid];
        lpos[tid] = ex;
        int node = sb * SBN + tid;
        if (node < NN) { offs[node] = sb * SBCAP + ex; deg[node] = lhist[tid]; }
    }
    __syncthreads();
    // in-place: region now becomes the CSR (block owns it exclusively)
    for (int i = tid; i < cnt; i += 1024) {
        int val = lstage[i];
        int slot = atomicAdd(&lpos[val & 511], 1);
        region[slot] = val >> 9;
    }
}

// ---------------- bf16 mean aggregation: one wave per node, 4 edges/group-iter ----------------
__global__ __launch_bounds__(256)
void k_aggregate_bf(const unsigned short* __restrict__ feat, const int* __restrict__ csr,
                    const int* __restrict__ offs, const int* __restrict__ deg,
                    unsigned short* __restrict__ outmean) {
    const int wid = threadIdx.x >> 6, lane = threadIdx.x & 63;
    const int q = lane >> 4, l4 = lane & 15;
    const int node = blockIdx.x * 4 + wid;
    if (node >= NN) return;
    int off = __builtin_amdgcn_readfirstlane(offs[node]);
    int dg  = __builtin_amdgcn_readfirstlane(deg[node]);
    const ush8* __restrict__ f8 = (const ush8*)feat;
    float acc[8];
    #pragma unroll
    for (int i = 0; i < 8; ++i) acc[i] = 0.f;
    int j = 0;
    for (; j + 8 <= dg; j += 8) {
        int e0 = csr[off + j + q];
        int e1 = csr[off + j + 4 + q];
        ush8 v0 = f8[(size_t)e0 * 16 + l4];
        ush8 v1 = f8[(size_t)e1 * 16 + l4];
        #pragma unroll
        for (int i = 0; i < 8; ++i) acc[i] += b2f(v0[i]) + b2f(v1[i]);
    }
    for (; j + 4 <= dg; j += 4) {
        int e0 = csr[off + j + q];
        ush8 v0 = f8[(size_t)e0 * 16 + l4];
        #pragma unroll
        for (int i = 0; i < 8; ++i) acc[i] += b2f(v0[i]);
    }
    int rem = dg - j;
    if (q < rem) {
        int e0 = csr[off + j + q];
        ush8 v0 = f8[(size_t)e0 * 16 + l4];
        #pragma unroll
        for (int i = 0; i < 8; ++i) acc[i] += b2f(v0[i]);
    }
    #pragma unroll
    for (int i = 0; i < 8; ++i) {
        acc[i] += __shfl_xor(acc[i], 16);
        acc[i] += __shfl_xor(acc[i], 32);
    }
    if (q == 0) {
        float inv = 1.0f / (float)(dg > 0 ? dg : 1);
        ush8 r;
        #pragma unroll
        for (int i = 0; i < 8; ++i) r[i] = f2bf(acc[i] * inv);
        ((ush8*)outmean)[(size_t)node * 16 + l4] = r;
    }
}

// ---------------- MFMA dual GEMM: out = Am@Wl + Ax@Wr + bias (+relu / +log_softmax) ----------------
template <int BN, bool RELU, bool OUTBF, bool LSM>
__global__ __launch_bounds__(256)
void k_gemm_mfma(const unsigned short* __restrict__ Am, const unsigned short* __restrict__ Ax,
                 const unsigned short* __restrict__ Wtl, const unsigned short* __restrict__ Wtr,
                 const float* __restrict__ bias, void* __restrict__ outp) {
    constexpr int BM = 128;
    constexpr int WAVES_N = BN / 64;          // 2 (BN=128) or 1 (BN=64)
    constexpr int WAVES_M = 4 / WAVES_N;      // 2 or 4
    constexpr int MR = BM / (WAVES_M * 16);   // 4 or 2
    constexpr int NR = 4;                     // 64 cols per wave
    __shared__ __align__(16) short As[BM * 40];   // 80B row stride -> uniform banks
    __shared__ __align__(16) short Ws[BN * 40];

    const int tid = threadIdx.x;
    const int wave = tid >> 6, lane = tid & 63;
    const int l15 = lane & 15, kg = lane >> 4;
    const int wc = wave % WAVES_N, wr = wave / WAVES_N;
    const int rowbase = wr * MR * 16;
    const int colbase = wc * 64;
    const int row0 = blockIdx.x * BM;

    f32x4 acc[MR][NR];
    #pragma unroll
    for (int mr = 0; mr < MR; ++mr)
        #pragma unroll
        for (int nr = 0; nr < NR; ++nr) acc[mr][nr] = (f32x4){0.f, 0.f, 0.f, 0.f};

    for (int s = 0; s < 2; ++s) {
        const unsigned short* __restrict__ A  = s ? Ax : Am;
        const unsigned short* __restrict__ Wt = s ? Wtr : Wtl;
        for (int kc = 0; kc < 128; kc += 32) {
            __syncthreads();
            #pragma unroll
            for (int i = 0; i < (BM * 4) / 256; ++i) {
                int c = tid + 256 * i; int r = c >> 2, g = c & 3;
                ush8 v = {0, 0, 0, 0, 0, 0, 0, 0};
                int grow = row0 + r;
                if (grow < NN) v = *(const ush8*)&A[(size_t)grow * 128 + kc + g * 8];
                *(ush8*)&As[r * 40 + g * 8] = v;
            }
            #pragma unroll
            for (int i = 0; i < (BN * 4) / 256; ++i) {
                int c = tid + 256 * i; int n = c >> 2, g = c & 3;
                *(ush8*)&Ws[n * 40 + g * 8] = *(const ush8*)&Wt[n * 128 + kc + g * 8];
            }
            __syncthreads();
            bf16x8 af[MR], bfr[NR];
            #pragma unroll
            for (int mr = 0; mr < MR; ++mr)
                af[mr] = *(const bf16x8*)&As[(rowbase + mr * 16 + l15) * 40 + kg * 8];
            #pragma unroll
            for (int nr = 0; nr < NR; ++nr)
                bfr[nr] = *(const bf16x8*)&Ws[(colbase + nr * 16 + l15) * 40 + kg * 8];
            #pragma unroll
            for (int mr = 0; mr < MR; ++mr)
                #pragma unroll
                for (int nr = 0; nr < NR; ++nr)
                    acc[mr][nr] = __builtin_amdgcn_mfma_f32_16x16x32_bf16(
                        af[mr], bfr[nr], acc[mr][nr], 0, 0, 0);
        }
    }
    // epilogue
    const int r4 = kg * 4;
    if (LSM) {
        // BN==64: each 16-lane group holds one full 64-col row per (mr,j).
        #pragma unroll
        for (int mr = 0; mr < MR; ++mr) {
            #pragma unroll
            for (int j = 0; j < 4; ++j) {
                int row = row0 + rowbase + mr * 16 + r4 + j;
                float v[NR];
                float m = -1e30f;
                #pragma unroll
                for (int nr = 0; nr < NR; ++nr) {
                    v[nr] = acc[mr][nr][j] + bias[nr * 16 + l15];
                    m = fmaxf(m, v[nr]);
                }
                #pragma unroll
                for (int d = 8; d >= 1; d >>= 1) m = fmaxf(m, __shfl_xor(m, d));
                float ssum = 0.f;
                #pragma unroll
                for (int nr = 0; nr < NR; ++nr) ssum += __expf(v[nr] - m);
                #pragma unroll
                for (int d = 8; d >= 1; d >>= 1) ssum += __shfl_xor(ssum, d);
                float lse = m + logf(ssum);
                if (row < NN) {
                    #pragma unroll
                    for (int nr = 0; nr < NR; ++nr)
                        ((float*)outp)[(size_t)row * 64 + nr * 16 + l15] = v[nr] - lse;
                }
            }
        }
    } else {
        #pragma unroll
        for (int mr = 0; mr < MR; ++mr) {
            #pragma unroll
            for (int nr = 0; nr < NR; ++nr) {
                int col = colbase + nr * 16 + l15;
                float bv = bias[col];
                #pragma unroll
                for (int j = 0; j < 4; ++j) {
                    int row = row0 + rowbase + mr * 16 + r4 + j;
                    if (row < NN) {
                        float v = acc[mr][nr][j] + bv;
                        if (RELU) v = fmaxf(v, 0.f);
                        if (OUTBF) ((unsigned short*)outp)[(size_t)row * BN + col] = f2bf(v);
                        else       ((float*)outp)[(size_t)row * BN + col] = v;
                    }
                }
            }
        }
    }
}

// ---------------- launch ----------------
extern "C" void kernel_launch(void* const* d_in, const int* in_sizes, int n_in,
                              void* d_out, int out_size, void* d_ws, size_t ws_size,
                              hipStream_t stream) {
    const float* x   = (const float*)d_in[0];
    const int* edges = (const int*)d_in[1];
    const float* W1l = (const float*)d_in[2];
    const float* b1  = (const float*)d_in[3];
    const float* W1r = (const float*)d_in[4];
    const float* W2l = (const float*)d_in[5];
    const float* b2  = (const float*)d_in[6];
    const float* W2r = (const float*)d_in[7];
    float* out = (float*)d_out;

    const int* src = edges;            // edge_index[0]
    const int* dst = edges + NE;       // edge_index[1]

    char* ws = (char*)d_ws;
    size_t o = 0;
    auto alloc = [&](size_t bytes) -> void* {
        void* p = ws + o;
        o = (o + bytes + 255) & ~(size_t)255;
        return p;
    };
    int* gcnt  = (int*)alloc((size_t)NSB * 4);
    int* pairs = (int*)alloc((size_t)NSB * SBCAP * 4);   // 8 MB; becomes CSR after sortB
    int* offs  = (int*)alloc((size_t)NN * 4);
    int* deg   = (int*)alloc((size_t)NN * 4);
    unsigned short* xb    = (unsigned short*)alloc((size_t)NN * 128 * 2);
    unsigned short* meanb = (unsigned short*)alloc((size_t)NN * 128 * 2);
    unsigned short* hb    = (unsigned short*)alloc((size_t)NN * 128 * 2);
    unsigned short* Wt1l  = (unsigned short*)alloc(128 * 128 * 2);
    unsigned short* Wt1r  = (unsigned short*)alloc(128 * 128 * 2);
    unsigned short* Wt2l  = (unsigned short*)alloc(64 * 128 * 2);
    unsigned short* Wt2r  = (unsigned short*)alloc(64 * 128 * 2);

    hipMemsetAsync(gcnt, 0, (size_t)NSB * 4, stream);

    // conversions
    k_cvt_x<<<2048, 256, 0, stream>>>(x, xb, (long)NN * 128 / 8);
    k_cvt_w<<<(128 * 128 + 255) / 256, 256, 0, stream>>>(W1l, Wt1l, 128);
    k_cvt_w<<<(128 * 128 + 255) / 256, 256, 0, stream>>>(W1r, Wt1r, 128);
    k_cvt_w<<<(64 * 128 + 255) / 256, 256, 0, stream>>>(W2l, Wt2l, 64);
    k_cvt_w<<<(64 * 128 + 255) / 256, 256, 0, stream>>>(W2r, Wt2r, 64);

    // CSR build: two-level LDS counting sort (coalesced writes, ~38K atomics total)
    k_binA<<<NBA, 1024, 0, stream>>>(src, dst, gcnt, pairs);
    k_sortB<<<NSB, 1024, 0, stream>>>(gcnt, pairs, offs, deg);

    const int GEMM_GRID = (NN + 127) / 128;   // 782
    // layer 1
    k_aggregate_bf<<<(NN + 3) / 4, 256, 0, stream>>>(xb, pairs, offs, deg, meanb);
    k_gemm_mfma<128, true, true, false><<<GEMM_GRID, 256, 0, stream>>>(meanb, xb, Wt1l, Wt1r, b1, hb);
    // layer 2 (log_softmax fused into GEMM epilogue)
    k_aggregate_bf<<<(NN + 3) / 4, 256, 0, stream>>>(hb, pairs, offs, deg, meanb);
    k_gemm_mfma<64, false, false, true><<<GEMM_GRID, 256, 0, stream>>>(meanb, hb, Wt2l, Wt2r, b2, out);
}

// Round 10
// 224.014 us; speedup vs baseline: 1.7530x; 1.0093x over previous
//
#include <hip/hip_runtime.h>
#include <math.h>

#define NN 100000
#define NE 1600000
#define SBN 512                      // nodes per super-bucket
#define NSB ((NN + SBN - 1) / SBN)   // 196 super-buckets
#define SBCAP 10240                  // per-super-bucket edge capacity (mean 8192)
#define EPB 8192                     // edges per binA block
#define NBA ((NE + EPB - 1) / EPB)   // 196 binA blocks

typedef __attribute__((ext_vector_type(8))) short bf16x8;   // 8 bf16 = 4 VGPR (MFMA A/B frag)
typedef __attribute__((ext_vector_type(8))) unsigned short ush8;
typedef __attribute__((ext_vector_type(4))) float f32x4;    // MFMA C/D frag

static __device__ __forceinline__ float b2f(unsigned short u) {
    return __uint_as_float(((unsigned int)u) << 16);
}
static __device__ __forceinline__ unsigned short f2bf(float f) {
    unsigned int u = __float_as_uint(f);
    u += 0x7fffu + ((u >> 16) & 1u);   // RNE
    return (unsigned short)(u >> 16);
}

// ---------------- conversions ----------------
__global__ __launch_bounds__(256)
void k_cvt_x(const float* __restrict__ in, unsigned short* __restrict__ outb, long total8) {
    long i = (long)blockIdx.x * 256 + threadIdx.x;
    long stride = (long)gridDim.x * 256;
    for (; i < total8; i += stride) {
        const float4* p = (const float4*)(in + i * 8);
        float4 a = p[0], b = p[1];
        ush8 r;
        r[0] = f2bf(a.x); r[1] = f2bf(a.y); r[2] = f2bf(a.z); r[3] = f2bf(a.w);
        r[4] = f2bf(b.x); r[5] = f2bf(b.y); r[6] = f2bf(b.z); r[7] = f2bf(b.w);
        *(ush8*)(outb + i * 8) = r;
    }
}

// W [128, N] f32 -> Wt [N, 128] bf16 (row-major over n)
__global__ __launch_bounds__(256)
void k_cvt_w(const float* __restrict__ W, unsigned short* __restrict__ Wt, int N) {
    int id = blockIdx.x * 256 + threadIdx.x;
    if (id < N * 128) {
        int n = id >> 7, k = id & 127;
        Wt[id] = f2bf(W[k * N + n]);
    }
}

// Wtcat[n][k]: n<64 -> W2l[k][n], else W2r[k][n-64]   (both [128,64] f32)
__global__ __launch_bounds__(256)
void k_cvt_wcat(const float* __restrict__ W2l, const float* __restrict__ W2r,
                unsigned short* __restrict__ Wt) {
    int id = blockIdx.x * 256 + threadIdx.x;
    if (id < 128 * 128) {
        int n = id >> 7, k = id & 127;
        float v = (n < 64) ? W2l[k * 64 + n] : W2r[k * 64 + (n - 64)];
        Wt[id] = f2bf(v);
    }
}

// ---------------- pass A: LDS-binned counting sort into 196 super-buckets ----------------
__global__ __launch_bounds__(1024)
void k_binA(const int* __restrict__ src, const int* __restrict__ dst,
            int* __restrict__ gcnt, int* __restrict__ pairs) {
    __shared__ int lsort[EPB];        // 32 KB
    __shared__ int lhist[256];
    __shared__ int lofs[256];         // exclusive offsets (immutable copy)
    __shared__ int lpos[NSB];
    __shared__ int gbase[NSB];
    const int tid = threadIdx.x;
    const int base = blockIdx.x * EPB;
    const int cnt = min(EPB, NE - base);

    int v[8], bn[8];
    #pragma unroll
    for (int k = 0; k < 8; ++k) {
        int i = k * 1024 + tid;
        if (i < cnt) {
            int d = dst[base + i], s = src[base + i];
            v[k] = (s << 9) | (d & 511);
            bn[k] = d >> 9;
        } else bn[k] = -1;
    }
    if (tid < 256) lhist[tid] = 0;
    __syncthreads();
    #pragma unroll
    for (int k = 0; k < 8; ++k) if (bn[k] >= 0) atomicAdd(&lhist[bn[k]], 1);
    __syncthreads();
    if (tid < 256) lofs[tid] = lhist[tid];
    __syncthreads();
    for (int d = 1; d < 256; d <<= 1) {
        int u = (tid < 256 && tid >= d) ? lofs[tid - d] : 0;
        __syncthreads();
        if (tid < 256) lofs[tid] += u;
        __syncthreads();
    }
    if (tid < 256) lofs[tid] -= lhist[tid];   // inclusive -> exclusive
    __syncthreads();
    if (tid < NSB) {
        lpos[tid] = lofs[tid];
        gbase[tid] = atomicAdd(&gcnt[tid], lhist[tid]);
    }
    __syncthreads();
    #pragma unroll
    for (int k = 0; k < 8; ++k) if (bn[k] >= 0) {
        int slot = atomicAdd(&lpos[bn[k]], 1);
        lsort[slot] = v[k];
    }
    __syncthreads();
    for (int i = tid; i < cnt; i += 1024) {
        int lo = 0, hi = NSB - 1;
        while (lo < hi) { int mid = (lo + hi + 1) >> 1; if (lofs[mid] <= i) lo = mid; else hi = mid - 1; }
        int off = gbase[lo] + (i - lofs[lo]);
        if (off < SBCAP)
            __builtin_nontemporal_store(lsort[i], &pairs[(size_t)lo * SBCAP + off]);
    }
}

// ---------------- pass B: per-super-bucket sort -> CSR (in place), deg/offs ----------------
__global__ __launch_bounds__(1024)
void k_sortB(const int* __restrict__ gcnt, int* __restrict__ pairs,
             int* __restrict__ offs, int* __restrict__ deg) {
    __shared__ int lstage[SBCAP];     // 40 KB
    __shared__ int lhist[SBN], lscan[SBN], lpos[SBN];
    const int sb = blockIdx.x, tid = threadIdx.x;
    const int cnt = min(gcnt[sb], SBCAP);
    int* __restrict__ region = pairs + (size_t)sb * SBCAP;

    for (int i = tid; i < cnt; i += 1024) lstage[i] = region[i];
    if (tid < SBN) lhist[tid] = 0;
    __syncthreads();
    for (int i = tid; i < cnt; i += 1024) atomicAdd(&lhist[lstage[i] & 511], 1);
    __syncthreads();
    if (tid < SBN) lscan[tid] = lhist[tid];
    __syncthreads();
    for (int d = 1; d < SBN; d <<= 1) {
        int u = (tid < SBN && tid >= d) ? lscan[tid - d] : 0;
        __syncthreads();
        if (tid < SBN) lscan[tid] += u;
        __syncthreads();
    }
    if (tid < SBN) {
        int ex = lscan[tid] - lhist[tid];
        lpos[tid] = ex;
        int node = sb * SBN + tid;
        if (node < NN) { offs[node] = sb * SBCAP + ex; deg[node] = lhist[tid]; }
    }
    __syncthreads();
    for (int i = tid; i < cnt; i += 1024) {
        int val = lstage[i];
        int slot = atomicAdd(&lpos[val & 511], 1);
        region[slot] = val >> 9;
    }
}

// ---------------- bf16 mean aggregation (layer 1): one wave per node ----------------
__global__ __launch_bounds__(256)
void k_aggregate_bf(const unsigned short* __restrict__ feat, const int* __restrict__ csr,
                    const int* __restrict__ offs, const int* __restrict__ deg,
                    unsigned short* __restrict__ outmean) {
    const int wid = threadIdx.x >> 6, lane = threadIdx.x & 63;
    const int q = lane >> 4, l4 = lane & 15;
    const int node = blockIdx.x * 4 + wid;
    if (node >= NN) return;
    int off = __builtin_amdgcn_readfirstlane(offs[node]);
    int dg  = __builtin_amdgcn_readfirstlane(deg[node]);
    const ush8* __restrict__ f8 = (const ush8*)feat;
    float acc[8];
    #pragma unroll
    for (int i = 0; i < 8; ++i) acc[i] = 0.f;
    int j = 0;
    for (; j + 8 <= dg; j += 8) {
        int e0 = csr[off + j + q];
        int e1 = csr[off + j + 4 + q];
        ush8 v0 = f8[(size_t)e0 * 16 + l4];
        ush8 v1 = f8[(size_t)e1 * 16 + l4];
        #pragma unroll
        for (int i = 0; i < 8; ++i) acc[i] += b2f(v0[i]) + b2f(v1[i]);
    }
    for (; j + 4 <= dg; j += 4) {
        int e0 = csr[off + j + q];
        ush8 v0 = f8[(size_t)e0 * 16 + l4];
        #pragma unroll
        for (int i = 0; i < 8; ++i) acc[i] += b2f(v0[i]);
    }
    int rem = dg - j;
    if (q < rem) {
        int e0 = csr[off + j + q];
        ush8 v0 = f8[(size_t)e0 * 16 + l4];
        #pragma unroll
        for (int i = 0; i < 8; ++i) acc[i] += b2f(v0[i]);
    }
    #pragma unroll
    for (int i = 0; i < 8; ++i) {
        acc[i] += __shfl_xor(acc[i], 16);
        acc[i] += __shfl_xor(acc[i], 32);
    }
    if (q == 0) {
        float inv = 1.0f / (float)(dg > 0 ? dg : 1);
        ush8 r;
        #pragma unroll
        for (int i = 0; i < 8; ++i) r[i] = f2bf(acc[i] * inv);
        ((ush8*)outmean)[(size_t)node * 16 + l4] = r;
    }
}

// ---------------- MFMA dual GEMM (layer 1): hb = relu(Am@Wl + Ax@Wr + b1) ----------------
template <int BN, bool RELU, bool OUTBF>
__global__ __launch_bounds__(256)
void k_gemm_mfma(const unsigned short* __restrict__ Am, const unsigned short* __restrict__ Ax,
                 const unsigned short* __restrict__ Wtl, const unsigned short* __restrict__ Wtr,
                 const float* __restrict__ bias, void* __restrict__ outp) {
    constexpr int BM = 128;
    constexpr int WAVES_N = BN / 64;
    constexpr int WAVES_M = 4 / WAVES_N;
    constexpr int MR = BM / (WAVES_M * 16);
    constexpr int NR = 4;
    __shared__ __align__(16) short As[BM * 40];
    __shared__ __align__(16) short Ws[BN * 40];

    const int tid = threadIdx.x;
    const int wave = tid >> 6, lane = tid & 63;
    const int l15 = lane & 15, kg = lane >> 4;
    const int wc = wave % WAVES_N, wr = wave / WAVES_N;
    const int rowbase = wr * MR * 16;
    const int colbase = wc * 64;
    const int row0 = blockIdx.x * BM;

    f32x4 acc[MR][NR];
    #pragma unroll
    for (int mr = 0; mr < MR; ++mr)
        #pragma unroll
        for (int nr = 0; nr < NR; ++nr) acc[mr][nr] = (f32x4){0.f, 0.f, 0.f, 0.f};

    for (int s = 0; s < 2; ++s) {
        const unsigned short* __restrict__ A  = s ? Ax : Am;
        const unsigned short* __restrict__ Wt = s ? Wtr : Wtl;
        for (int kc = 0; kc < 128; kc += 32) {
            __syncthreads();
            #pragma unroll
            for (int i = 0; i < (BM * 4) / 256; ++i) {
                int c = tid + 256 * i; int r = c >> 2, g = c & 3;
                ush8 v = {0, 0, 0, 0, 0, 0, 0, 0};
                int grow = row0 + r;
                if (grow < NN) v = *(const ush8*)&A[(size_t)grow * 128 + kc + g * 8];
                *(ush8*)&As[r * 40 + g * 8] = v;
            }
            #pragma unroll
            for (int i = 0; i < (BN * 4) / 256; ++i) {
                int c = tid + 256 * i; int n = c >> 2, g = c & 3;
                *(ush8*)&Ws[n * 40 + g * 8] = *(const ush8*)&Wt[n * 128 + kc + g * 8];
            }
            __syncthreads();
            bf16x8 af[MR], bfr[NR];
            #pragma unroll
            for (int mr = 0; mr < MR; ++mr)
                af[mr] = *(const bf16x8*)&As[(rowbase + mr * 16 + l15) * 40 + kg * 8];
            #pragma unroll
            for (int nr = 0; nr < NR; ++nr)
                bfr[nr] = *(const bf16x8*)&Ws[(colbase + nr * 16 + l15) * 40 + kg * 8];
            #pragma unroll
            for (int mr = 0; mr < MR; ++mr)
                #pragma unroll
                for (int nr = 0; nr < NR; ++nr)
                    acc[mr][nr] = __builtin_amdgcn_mfma_f32_16x16x32_bf16(
                        af[mr], bfr[nr], acc[mr][nr], 0, 0, 0);
        }
    }
    const int r4 = kg * 4;
    #pragma unroll
    for (int mr = 0; mr < MR; ++mr) {
        #pragma unroll
        for (int nr = 0; nr < NR; ++nr) {
            int col = colbase + nr * 16 + l15;
            float bv = bias[col];
            #pragma unroll
            for (int j = 0; j < 4; ++j) {
                int row = row0 + rowbase + mr * 16 + r4 + j;
                if (row < NN) {
                    float v = acc[mr][nr][j] + bv;
                    if (RELU) v = fmaxf(v, 0.f);
                    if (OUTBF) ((unsigned short*)outp)[(size_t)row * BN + col] = f2bf(v);
                    else       ((float*)outp)[(size_t)row * BN + col] = v;
                }
            }
        }
    }
}

// ---------------- cat GEMM (layer 2): g = hb@W2l (bf16), z = hb@W2r + b2 (bf16) ----------------
// B = [W2l | W2r] pre-transposed to Wt[128][128]; single A pass, split writeout.
__global__ __launch_bounds__(256)
void k_gemm_cat(const unsigned short* __restrict__ A, const unsigned short* __restrict__ Wt,
                const float* __restrict__ b2,
                unsigned short* __restrict__ g, unsigned short* __restrict__ z) {
    constexpr int BM = 128, BN = 128, MR = 4, NR = 4;
    __shared__ __align__(16) short As[BM * 40];
    __shared__ __align__(16) short Ws[BN * 40];

    const int tid = threadIdx.x;
    const int wave = tid >> 6, lane = tid & 63;
    const int l15 = lane & 15, kg = lane >> 4;
    const int wc = wave % 2, wr = wave / 2;
    const int rowbase = wr * MR * 16;
    const int colbase = wc * 64;
    const int row0 = blockIdx.x * BM;

    f32x4 acc[MR][NR];
    #pragma unroll
    for (int mr = 0; mr < MR; ++mr)
        #pragma unroll
        for (int nr = 0; nr < NR; ++nr) acc[mr][nr] = (f32x4){0.f, 0.f, 0.f, 0.f};

    for (int kc = 0; kc < 128; kc += 32) {
        __syncthreads();
        #pragma unroll
        for (int i = 0; i < 2; ++i) {
            int c = tid + 256 * i; int r = c >> 2, gg = c & 3;
            ush8 v = {0, 0, 0, 0, 0, 0, 0, 0};
            int grow = row0 + r;
            if (grow < NN) v = *(const ush8*)&A[(size_t)grow * 128 + kc + gg * 8];
            *(ush8*)&As[r * 40 + gg * 8] = v;
        }
        #pragma unroll
        for (int i = 0; i < 2; ++i) {
            int c = tid + 256 * i; int n = c >> 2, gg = c & 3;
            *(ush8*)&Ws[n * 40 + gg * 8] = *(const ush8*)&Wt[n * 128 + kc + gg * 8];
        }
        __syncthreads();
        bf16x8 af[MR], bfr[NR];
        #pragma unroll
        for (int mr = 0; mr < MR; ++mr)
            af[mr] = *(const bf16x8*)&As[(rowbase + mr * 16 + l15) * 40 + kg * 8];
        #pragma unroll
        for (int nr = 0; nr < NR; ++nr)
            bfr[nr] = *(const bf16x8*)&Ws[(colbase + nr * 16 + l15) * 40 + kg * 8];
        #pragma unroll
        for (int mr = 0; mr < MR; ++mr)
            #pragma unroll
            for (int nr = 0; nr < NR; ++nr)
                acc[mr][nr] = __builtin_amdgcn_mfma_f32_16x16x32_bf16(
                    af[mr], bfr[nr], acc[mr][nr], 0, 0, 0);
    }
    const int r4 = kg * 4;
    #pragma unroll
    for (int mr = 0; mr < MR; ++mr) {
        #pragma unroll
        for (int nr = 0; nr < NR; ++nr) {
            int col = colbase + nr * 16 + l15;
            float bv = (col >= 64) ? b2[col - 64] : 0.f;
            #pragma unroll
            for (int j = 0; j < 4; ++j) {
                int row = row0 + rowbase + mr * 16 + r4 + j;
                if (row < NN) {
                    float v = acc[mr][nr][j] + bv;
                    unsigned short bv16 = f2bf(v);
                    if (col < 64) g[(size_t)row * 64 + col] = bv16;
                    else          z[(size_t)row * 64 + (col - 64)] = bv16;
                }
            }
        }
    }
}

// ---------------- fused layer-2 tail: out = log_softmax(mean(g) + z) ----------------
// One wave per node; rows of g are 64 bf16 = 128B = 8 lanes x 16B -> 8 edges/instr.
__global__ __launch_bounds__(256)
void k_agg_lsm(const unsigned short* __restrict__ gbuf, const unsigned short* __restrict__ zbuf,
               const int* __restrict__ csr, const int* __restrict__ offs,
               const int* __restrict__ deg, float* __restrict__ out) {
    const int wid = threadIdx.x >> 6, lane = threadIdx.x & 63;
    const int g8 = lane >> 3, l8 = lane & 7;
    const int node = blockIdx.x * 4 + wid;
    if (node >= NN) return;
    int off = __builtin_amdgcn_readfirstlane(offs[node]);
    int dg  = __builtin_amdgcn_readfirstlane(deg[node]);
    const ush8* __restrict__ f8 = (const ush8*)gbuf;
    float acc[8];
    #pragma unroll
    for (int i = 0; i < 8; ++i) acc[i] = 0.f;
    int j = 0;
    for (; j + 16 <= dg; j += 16) {
        int e0 = csr[off + j + g8];
        int e1 = csr[off + j + 8 + g8];
        ush8 v0 = f8[(size_t)e0 * 8 + l8];
        ush8 v1 = f8[(size_t)e1 * 8 + l8];
        #pragma unroll
        for (int i = 0; i < 8; ++i) acc[i] += b2f(v0[i]) + b2f(v1[i]);
    }
    for (; j + 8 <= dg; j += 8) {
        int e0 = csr[off + j + g8];
        ush8 v0 = f8[(size_t)e0 * 8 + l8];
        #pragma unroll
        for (int i = 0; i < 8; ++i) acc[i] += b2f(v0[i]);
    }
    int rem = dg - j;
    if (g8 < rem) {
        int e0 = csr[off + j + g8];
        ush8 v0 = f8[(size_t)e0 * 8 + l8];
        #pragma unroll
        for (int i = 0; i < 8; ++i) acc[i] += b2f(v0[i]);
    }
    #pragma unroll
    for (int i = 0; i < 8; ++i) {
        acc[i] += __shfl_xor(acc[i], 8);
        acc[i] += __shfl_xor(acc[i], 16);
        acc[i] += __shfl_xor(acc[i], 32);
    }
    float inv = 1.0f / (float)(dg > 0 ? dg : 1);
    ush8 zv = ((const ush8*)zbuf)[(size_t)node * 8 + l8];
    float v[8];
    float m = -1e30f;
    #pragma unroll
    for (int i = 0; i < 8; ++i) {
        v[i] = acc[i] * inv + b2f(zv[i]);
        m = fmaxf(m, v[i]);
    }
    #pragma unroll
    for (int d = 4; d >= 1; d >>= 1) m = fmaxf(m, __shfl_xor(m, d));
    float ss = 0.f;
    #pragma unroll
    for (int i = 0; i < 8; ++i) ss += __expf(v[i] - m);
    #pragma unroll
    for (int d = 4; d >= 1; d >>= 1) ss += __shfl_xor(ss, d);
    float lse = m + logf(ss);
    if (g8 == 0) {
        float4 o0 = make_float4(v[0] - lse, v[1] - lse, v[2] - lse, v[3] - lse);
        float4 o1 = make_float4(v[4] - lse, v[5] - lse, v[6] - lse, v[7] - lse);
        *(float4*)&out[(size_t)node * 64 + l8 * 8]     = o0;
        *(float4*)&out[(size_t)node * 64 + l8 * 8 + 4] = o1;
    }
}

// ---------------- launch ----------------
extern "C" void kernel_launch(void* const* d_in, const int* in_sizes, int n_in,
                              void* d_out, int out_size, void* d_ws, size_t ws_size,
                              hipStream_t stream) {
    const float* x   = (const float*)d_in[0];
    const int* edges = (const int*)d_in[1];
    const float* W1l = (const float*)d_in[2];
    const float* b1  = (const float*)d_in[3];
    const float* W1r = (const float*)d_in[4];
    const float* W2l = (const float*)d_in[5];
    const float* b2  = (const float*)d_in[6];
    const float* W2r = (const float*)d_in[7];
    float* out = (float*)d_out;

    const int* src = edges;            // edge_index[0]
    const int* dst = edges + NE;       // edge_index[1]

    char* ws = (char*)d_ws;
    size_t o = 0;
    auto alloc = [&](size_t bytes) -> void* {
        void* p = ws + o;
        o = (o + bytes + 255) & ~(size_t)255;
        return p;
    };
    int* gcnt  = (int*)alloc((size_t)NSB * 4);
    int* pairs = (int*)alloc((size_t)NSB * SBCAP * 4);   // becomes CSR after sortB
    int* offs  = (int*)alloc((size_t)NN * 4);
    int* deg   = (int*)alloc((size_t)NN * 4);
    unsigned short* xb    = (unsigned short*)alloc((size_t)NN * 128 * 2);
    unsigned short* meanb = (unsigned short*)alloc((size_t)NN * 128 * 2);
    unsigned short* hb    = (unsigned short*)alloc((size_t)NN * 128 * 2);
    unsigned short* gbuf  = (unsigned short*)alloc((size_t)NN * 64 * 2);
    unsigned short* zbuf  = (unsigned short*)alloc((size_t)NN * 64 * 2);
    unsigned short* Wt1l  = (unsigned short*)alloc(128 * 128 * 2);
    unsigned short* Wt1r  = (unsigned short*)alloc(128 * 128 * 2);
    unsigned short* Wtcat = (unsigned short*)alloc(128 * 128 * 2);

    hipMemsetAsync(gcnt, 0, (size_t)NSB * 4, stream);

    // conversions
    k_cvt_x<<<2048, 256, 0, stream>>>(x, xb, (long)NN * 128 / 8);
    k_cvt_w<<<(128 * 128 + 255) / 256, 256, 0, stream>>>(W1l, Wt1l, 128);
    k_cvt_w<<<(128 * 128 + 255) / 256, 256, 0, stream>>>(W1r, Wt1r, 128);
    k_cvt_wcat<<<(128 * 128 + 255) / 256, 256, 0, stream>>>(W2l, W2r, Wtcat);

    // CSR build: two-level LDS counting sort
    k_binA<<<NBA, 1024, 0, stream>>>(src, dst, gcnt, pairs);
    k_sortB<<<NSB, 1024, 0, stream>>>(gcnt, pairs, offs, deg);

    const int GEMM_GRID = (NN + 127) / 128;   // 782
    // layer 1
    k_aggregate_bf<<<(NN + 3) / 4, 256, 0, stream>>>(xb, pairs, offs, deg, meanb);
    k_gemm_mfma<128, true, true><<<GEMM_GRID, 256, 0, stream>>>(meanb, xb, Wt1l, Wt1r, b1, hb);
    // layer 2: g = h@W2l, z = h@W2r + b2 first (mean commutes with linear map),
    // then 64-wide gather-mean + add z + log_softmax fused.
    k_gemm_cat<<<GEMM_GRID, 256, 0, stream>>>(hb, Wtcat, b2, gbuf, zbuf);
    k_agg_lsm<<<(NN + 3) / 4, 256, 0, stream>>>(gbuf, zbuf, pairs, offs, deg, out);
}